// Round 9
// baseline (9724.397 us; speedup 1.0000x reference)
//
#include <hip/hip_runtime.h>
#include <math.h>

#define B_    32
#define P_    4096
#define N_    1024
#define POS_  10
#define PP    (P_ + 2)     // padded phoneme rows (guard top/bottom)
#define NP    (N_ + 2)     // padded note rows
#define GB    8            // batches per phase-A chunk
#define NCHK  (B_ / GB)    // 4 phase-A chunks
#define TCH   256          // LSTM time chunk
#define NTCH  (N_ / TCH)   // 4 time chunks
#define X0S   280          // X0b row stride (bf16): K_conv1 = 2*280+272 = 832 (mult of 32)
#define ENCS  288          // enc row stride (bf16): K mult of 32

typedef unsigned short u16;
typedef _Float16 h2_t __attribute__((ext_vector_type(2)));
typedef unsigned u32x4 __attribute__((ext_vector_type(4)));
typedef short s16x8 __attribute__((ext_vector_type(8)));     // 8 bf16 (4 VGPRs)
typedef float f32x4 __attribute__((ext_vector_type(4)));     // MFMA acc

// ---------------- helpers ----------------
__device__ __forceinline__ float sigmoidf_(float x) { return 1.f / (1.f + __expf(-x)); }
__device__ __forceinline__ float tanhf_(float x) {
  float t = fminf(fmaxf(x, -30.f), 30.f);
  float e = __expf(2.f * t);
  return (e - 1.f) / (e + 1.f);
}
__device__ __forceinline__ float bf2f(u16 u) { return __uint_as_float(((unsigned)u) << 16); }
__device__ __forceinline__ u16 f2bf(float f) {
  unsigned u = __float_as_uint(f);
  unsigned r = u + 0x7FFFu + ((u >> 16) & 1u);
  return (u16)(r >> 16);
}
__device__ __forceinline__ u16 f2h_bits(float x) {
  _Float16 hh = (_Float16)x; u16 u; __builtin_memcpy(&u, &hh, 2); return u;
}
__device__ __forceinline__ unsigned pack2h(float lo, float hi) {
  return (unsigned)f2h_bits(lo) | ((unsigned)f2h_bits(hi) << 16);
}
__device__ __forceinline__ float dot2(unsigned w, unsigned h, float acc) {
  return __builtin_amdgcn_fdot2(__builtin_bit_cast(h2_t, w), __builtin_bit_cast(h2_t, h), acc, false);
}
#define DOT4(acc, wq, hq) \
  acc = dot2((wq).x, (hq).x, acc); acc = dot2((wq).y, (hq).y, acc); \
  acc = dot2((wq).z, (hq).z, acc); acc = dot2((wq).w, (hq).w, acc);

#define REP24(X) X(0)X(1)X(2)X(3)X(4)X(5)X(6)X(7)X(8)X(9)X(10)X(11)X(12)X(13)X(14)X(15)X(16)X(17)X(18)X(19)X(20)X(21)X(22)X(23)
#define REP8(X)  X(0)X(1)X(2)X(3)X(4)X(5)X(6)X(7)

__device__ __forceinline__ void stc(float* p, float v) { *p = v; }
__device__ __forceinline__ void stc(u16* p, float v)   { *p = f2bf(v); }

// ---------------- diagnostics ----------------
__global__ void fill_sentinel_kernel(float* out, int n, float v) {
  int i = blockIdx.x * 256 + threadIdx.x;
  if (i < n) out[i] = v;
}

// ---------------- zero guards ----------------
__global__ void zero_bf_guards_kernel(u16* X0b, u16* X1b) {
  int cb = blockIdx.x, t = threadIdx.x;
  for (int c = t; c < X0S; c += 256) {
    X0b[((long)cb * PP + 0) * X0S + c] = 0;
    X0b[((long)cb * PP + PP - 1) * X0S + c] = 0;
  }
  if (t < 256) {
    X1b[((long)cb * PP + 0) * 256 + t] = 0;
    X1b[((long)cb * PP + PP - 1) * 256 + t] = 0;
  }
}
__global__ void zero_y1p_guards_kernel(u16* Y1p) {
  int b = blockIdx.x, t = threadIdx.x;
  for (int c = t; c < 512; c += 256) {
    Y1p[((long)b * NP + 0) * 512 + c] = 0;
    Y1p[((long)b * NP + NP - 1) * 512 + c] = 0;
  }
}
__global__ void zero_c3p_guards_kernel(float* C3p) {
  int b = blockIdx.x, t = threadIdx.x;
  if (t < 256) {
    C3p[((long)b * NP + 0) * 256 + t] = 0.f;
    C3p[((long)b * NP + NP - 1) * 256 + t] = 0.f;
  }
}

// ---------------- embedding (chunked, bf16 out, stride 280) ----------------
__global__ void embed_bf16_kernel(const int* __restrict__ seq, const int* __restrict__ order,
                                  const float* __restrict__ emb, const float* __restrict__ pos_emb,
                                  u16* __restrict__ X0b, int b0) {
  long i = (long)blockIdx.x * 256 + threadIdx.x;
  const long total = (long)GB * P_ * X0S;
  if (i >= total) return;
  int c = (int)(i % X0S);
  long bp = i / X0S;
  int p = (int)(bp % P_);
  int cb = (int)(bp / P_);
  int b = b0 + cb;
  float v = 0.f;
  if (c < 256)      v = emb[(long)seq[(long)b * P_ + p] * 256 + c];
  else if (c < 266) v = pos_emb[(long)order[(long)b * P_ + p] * POS_ + (c - 256)];
  X0b[((long)cb * PP + p + 1) * X0S + c] = f2bf(v);
}

// ---------------- weight repacks ----------------
// conv w[co][ci][3] -> Bt[co][Kpad] bf16, k = r*strideA + ci; optional lo residual
__global__ void repack_conv_bt_kernel(const float* __restrict__ w, u16* __restrict__ hi,
                                      u16* __restrict__ lo, int CinReal, int strideA,
                                      int Kpad, int Cout) {
  long i = (long)blockIdx.x * 256 + threadIdx.x;
  if (i >= (long)Cout * Kpad) return;
  int co = (int)(i / Kpad), k = (int)(i - (long)co * Kpad);
  int r = k / strideA, ci = k - r * strideA;
  float v = (r < 3 && ci < CinReal) ? w[((long)co * CinReal + ci) * 3 + r] : 0.f;
  u16 h = f2bf(v);
  hi[i] = h;
  if (lo) lo[i] = f2bf(v - bf2f(h));
}
// dense w[co(1024)][k] -> Bt[j][Kpad] bf16 (hi+lo), PERMUTED: co = R(j)=(j&3)*256+(j>>2)
__global__ void repack_dense_bt_kernel(const float* __restrict__ w, u16* __restrict__ hi,
                                       u16* __restrict__ lo, int CinReal, int Kpad) {
  long i = (long)blockIdx.x * 256 + threadIdx.x;
  if (i >= 1024L * Kpad) return;
  int j = (int)(i / Kpad), k = (int)(i - (long)j * Kpad);
  int co = (j & 3) * 256 + (j >> 2);
  float v = (k < CinReal) ? w[(long)co * CinReal + k] : 0.f;
  u16 h = f2bf(v);
  hi[i] = h;
  lo[i] = f2bf(v - bf2f(h));
}
// Whh k<192 slice -> per-unit register quads:
// Wv[(((d*24 + kq)*4 + gate)*256) + u] = fp16 pairs of Whh[gate*256+u][kq*8 .. +8)
__global__ void repack_whh_reg_kernel(const float* __restrict__ whh, uint4* __restrict__ Wv) {
  long i = (long)blockIdx.x * 256 + threadIdx.x;
  if (i >= 49152) return;
  int u = (int)(i & 255);
  int gt = (int)((i >> 8) & 3);
  int t = (int)(i >> 10);          // 0..95
  int kq = t % 24, d = t / 24;
  int R = gt * 256 + u;
  const float* wr = whh + ((long)d * 1024 + R) * 256;
  uint4 o; unsigned* op = (unsigned*)&o;
#pragma unroll
  for (int q = 0; q < 4; q++) {
    int k = kq * 8 + 2 * q;
    op[q] = pack2h(wr[k], wr[k + 1]);
  }
  Wv[i] = o;
}
// Whh k in [192,256) -> LDS-resident per-unit quads:
// Ws[(((d*8 + kq2)*4 + gate)*256) + u], k = 192 + kq2*8 + 2q
__global__ void repack_whh_lds_kernel(const float* __restrict__ whh, uint4* __restrict__ Ws) {
  long i = (long)blockIdx.x * 256 + threadIdx.x;
  if (i >= 16384) return;
  int u = (int)(i & 255);
  int gt = (int)((i >> 8) & 3);
  int t = (int)(i >> 10);          // 0..15
  int kq2 = t & 7, d = t >> 3;
  int R = gt * 256 + u;
  const float* wr = whh + ((long)d * 1024 + R) * 256;
  uint4 o; unsigned* op = (unsigned*)&o;
#pragma unroll
  for (int q = 0; q < 4; q++) {
    int k = 192 + kq2 * 8 + 2 * q;
    op[q] = pack2h(wr[k], wr[k + 1]);
  }
  Ws[i] = o;
}
__global__ void bias_sum_perm_kernel(const float* __restrict__ a, const float* __restrict__ b,
                                     float* __restrict__ dst) {
  int i = blockIdx.x * 256 + threadIdx.x;
  if (i >= 2048) return;
  int d = i >> 10, j = i & 1023;
  int R = (j & 3) * 256 + (j >> 2);
  dst[i] = a[d * 1024 + R] + b[d * 1024 + R];
}
__global__ void repack_conv4_w_kernel(const float* __restrict__ w, float* __restrict__ dst) {
  int i = blockIdx.x * 256 + threadIdx.x;
  if (i < 768) { int r = i >> 8, ci = i & 255; dst[i] = w[ci * 3 + r]; }
}

// ---------------- MFMA rows-GEMM: C = A_rows @ Bt^T + bias ----------------
template <typename CT, bool SPLIT>
__global__ __launch_bounds__(256) void gemm_mfma_kernel(
    const u16* __restrict__ A, const u16* __restrict__ Bt, const u16* __restrict__ Bt2,
    const float* __restrict__ bias, CT* __restrict__ C,
    int N, int Kpad, int Mb,
    long aBatchStride, int aRowStride,
    long cBatchStride, int cRowStride, int relu) {
  int tid = threadIdx.x;
  int wave = tid >> 6, lane = tid & 63;
  int lrow = lane & 15, lk = (lane >> 4) * 8;
  int row0 = blockIdx.x * 64 + wave * 16;
  int col0 = blockIdx.y * 64;
  int grow = row0 + lrow;
  int b_ = grow / Mb, m_ = grow - b_ * Mb;
  const u16* arow = A + (long)b_ * aBatchStride + (long)m_ * aRowStride + lk;
  const u16* bp0 = Bt + (long)(col0 + lrow) * Kpad + lk;
  const u16* bq0 = SPLIT ? (Bt2 + (long)(col0 + lrow) * Kpad + lk) : bp0;
  f32x4 acc0 = {0.f, 0.f, 0.f, 0.f};
  f32x4 acc1 = acc0, acc2 = acc0, acc3 = acc0;
  for (int kk = 0; kk < Kpad; kk += 32) {
    s16x8 av = *(const s16x8*)(arow + kk);
    acc0 = __builtin_amdgcn_mfma_f32_16x16x32_bf16(av, *(const s16x8*)(bp0 + kk), acc0, 0, 0, 0);
    acc1 = __builtin_amdgcn_mfma_f32_16x16x32_bf16(av, *(const s16x8*)(bp0 + 16L * Kpad + kk), acc1, 0, 0, 0);
    acc2 = __builtin_amdgcn_mfma_f32_16x16x32_bf16(av, *(const s16x8*)(bp0 + 32L * Kpad + kk), acc2, 0, 0, 0);
    acc3 = __builtin_amdgcn_mfma_f32_16x16x32_bf16(av, *(const s16x8*)(bp0 + 48L * Kpad + kk), acc3, 0, 0, 0);
    if (SPLIT) {
      acc0 = __builtin_amdgcn_mfma_f32_16x16x32_bf16(av, *(const s16x8*)(bq0 + kk), acc0, 0, 0, 0);
      acc1 = __builtin_amdgcn_mfma_f32_16x16x32_bf16(av, *(const s16x8*)(bq0 + 16L * Kpad + kk), acc1, 0, 0, 0);
      acc2 = __builtin_amdgcn_mfma_f32_16x16x32_bf16(av, *(const s16x8*)(bq0 + 32L * Kpad + kk), acc2, 0, 0, 0);
      acc3 = __builtin_amdgcn_mfma_f32_16x16x32_bf16(av, *(const s16x8*)(bq0 + 48L * Kpad + kk), acc3, 0, 0, 0);
    }
  }
  int erow = row0 + (lane >> 4) * 4;
  int b2 = erow / Mb, m2 = erow - b2 * Mb;
  CT* cbase = C + (long)b2 * cBatchStride + (long)m2 * cRowStride + col0 + lrow;
#define EPI(cc, accv) { \
    float bv = bias[col0 + (cc) * 16 + lrow]; \
    float v0 = accv[0] + bv, v1 = accv[1] + bv, v2 = accv[2] + bv, v3 = accv[3] + bv; \
    if (relu) { v0 = fmaxf(v0, 0.f); v1 = fmaxf(v1, 0.f); v2 = fmaxf(v2, 0.f); v3 = fmaxf(v3, 0.f); } \
    stc(cbase + 0L * cRowStride + (cc) * 16, v0); \
    stc(cbase + 1L * cRowStride + (cc) * 16, v1); \
    stc(cbase + 2L * cRowStride + (cc) * 16, v2); \
    stc(cbase + 3L * cRowStride + (cc) * 16, v3); }
  EPI(0, acc0) EPI(1, acc1) EPI(2, acc2) EPI(3, acc3)
#undef EPI
}

// ---------------- note-segment scan: parallel runs-scan ----------------
__global__ __launch_bounds__(256) void seg_scan_kernel(const int* __restrict__ seq,
                                int* __restrict__ nstart, int* __restrict__ nlen) {
  __shared__ unsigned char v[P_];
  __shared__ int sc[2][256];
  int b = blockIdx.x, tid = threadIdx.x;
  for (int i = tid; i < P_; i += 256) {
    int s = seq[(long)b * P_ + i];
    v[i] = (s > 1 && i != P_ - 1) ? 1 : 0;   // last position never included
  }
  for (int n = tid; n < N_; n += 256) { nstart[b * N_ + n] = 0; nlen[b * N_ + n] = 0; }
  __syncthreads();
  int base = tid << 4;
  int c = 0;
#pragma unroll
  for (int i = 0; i < 16; i++) {
    int p = base + i;
    int val = v[p];
    int prev = p ? v[p - 1] : 0;
    c += val & (prev ^ 1);
  }
  sc[0][tid] = c;
  __syncthreads();
  int cur = 0;
  for (int d = 1; d < 256; d <<= 1) {
    int x = sc[cur][tid];
    if (tid >= d) x += sc[cur][tid - d];
    sc[cur ^ 1][tid] = x;
    cur ^= 1;
    __syncthreads();
  }
  int sg = tid ? sc[cur][tid - 1] : 0;
  for (int i = 0; i < 16; i++) {
    int p = base + i;
    int val = v[p];
    int prev = p ? v[p - 1] : 0;
    if (val && !prev) {
      if (sg < N_) {
        int len = 0, q = p;
        while (q < P_ && v[q]) { len++; q++; }
        nstart[b * N_ + sg] = p;
        nlen[b * N_ + sg] = len;
      }
      sg++;
    }
  }
}

// ---------------- segment mean + enc (bf16 in/out, stride 288) ----------------
__global__ __launch_bounds__(256) void agg_enc_kernel(
    const u16* __restrict__ X2b, const int* __restrict__ nstart, const int* __restrict__ nlen,
    const float* __restrict__ dur, u16* __restrict__ enc, int b0) {
  int n = blockIdx.x, gb = blockIdx.y;
  int b = b0 + gb;
  int d = threadIdx.x;
  int len = nlen[b * N_ + n], st = nstart[b * N_ + n];
  float acc = 0.f;
  for (int i = 0; i < len; i++) acc += bf2f(X2b[((long)gb * PP + st + 1 + i) * 256 + d]);
  float m = (len > 0) ? acc / (float)len : 0.f;
  long e = ((long)b * N_ + n) * ENCS;
  enc[e + d] = f2bf(m);
  if (d == 0) {
    float dd = dur[b * N_ + n];
    enc[e + 256] = f2bf(dd);
    enc[e + 257] = f2bf(1.f / (dd + 1.f));
  }
  if (d >= 2 && d < 32) enc[e + 256 + d] = 0;  // zero tail 258..287
}

// ---------------- LSTM recurrence v7: unit-per-thread, 1 wave/SIMD ----------------
// 64 WGs (chain = dir*32+b), 256 threads; thread u owns unit u's FOUR gate rows
// (i,f,g,o), K=256 each. Gates computed LOCALLY from the thread's own 4 accs:
// no zb round-trip, no half-idle phase; double-buffered hb -> ONE barrier/step.
// Z layout (perm R(j)=(j&3)*256+(j>>2)) already gives thread u its 4 gate pre-
// activations as one coalesced float4 at Zb[t*1024 + 4u].
// Weights: k<192 in 96 NAMED u32x4 quads (384 VGPRs, budget 512 at 1 wave/SIMD
// via waves_per_eu(1,1) -- no occupancy incentive to demote); k>=192 in 128KB LDS.
#define REC_LDS_BYTES (131072 + 2048)
__global__ __attribute__((amdgpu_waves_per_eu(1, 1))) __launch_bounds__(256)
void lstm_rec2_kernel(
    const float* __restrict__ Z,      // [2][32][TCH][1024] fp32, permuted cols
    const u32x4* __restrict__ Wv,     // [2][24kq][4gate][256u] fp16 quads (k<192)
    const u32x4* __restrict__ Ws,     // [2][8kq][4gate][256u] fp16 quads (k>=192)
    float* __restrict__ state,        // [64][2][256]
    u16* __restrict__ Y, int yRowsPerB, int yPad, int r) {
  extern __shared__ char smem[];
  u32x4* WL = (u32x4*)smem;                       // 8192 quads (128 KB)
  u16*   hb = (u16*)(smem + 131072);              // [2][256] fp16 (double buffer)

  int chain = blockIdx.x;
  int d = chain >> 5, b = chain & 31;
  int u = threadIdx.x;
  const float* Zb = Z + (long)(d * 32 + b) * (TCH * 1024);

  // stage LDS weights (linear copy; layout pre-baked by repack)
  for (int iq = 0; iq < 32; ++iq) {
    int q = iq * 256 + u;
    WL[q] = Ws[(long)d * 8192 + q];
  }
  // load register weights into 96 NAMED quads (384 VGPRs), pinned against remat
  const u32x4* WvD = Wv + (long)d * 24576 + u;
#define DECLW(i) u32x4 wI##i, wF##i, wG##i, wO##i;
  REP24(DECLW)
#undef DECLW
#define LOADW(i) { const u32x4* bp = WvD + (long)(i) * 1024; \
  wI##i = bp[0]; wF##i = bp[256]; wG##i = bp[512]; wO##i = bp[768]; }
  REP24(LOADW)
#undef LOADW
#define PINW(i) asm volatile("" : "+v"(wI##i), "+v"(wF##i), "+v"(wG##i), "+v"(wO##i));
  REP24(PINW)
#undef PINW

  float h_reg = 0.f, c_reg = 0.f;
  if (r > 0) {
    h_reg = state[(chain * 2 + 0) * 256 + u];
    c_reg = state[(chain * 2 + 1) * 256 + u];
  }
  hb[u] = f2h_bits(h_reg);                         // buffer 0
  __syncthreads();

  int t0 = (d == 0) ? r * TCH : (NTCH - 1 - r) * TCH;
  int tcf = d ? (TCH - 1) : 0;
  float4 zpre = *(const float4*)(Zb + (long)tcf * 1024 + 4 * u);

  for (int tt = 0; tt < TCH; ++tt) {
    int cur = tt & 1;
    float ai = zpre.x, af = zpre.y, ag = zpre.z, ao = zpre.w;
    if (tt + 1 < TCH) {                            // prefetch next step's z (coalesced)
      int tc2 = d ? (TCH - 2 - tt) : (tt + 1);
      zpre = *(const float4*)(Zb + (long)tc2 * 1024 + 4 * u);
    }
    const u32x4* hqc = (const u32x4*)(hb + cur * 256);   // 32 h quads (broadcast reads)
#define MACW(i) { u32x4 hq = hqc[i]; \
  DOT4(ai, wI##i, hq); DOT4(af, wF##i, hq); DOT4(ag, wG##i, hq); DOT4(ao, wO##i, hq); }
    REP24(MACW)
#undef MACW
#define MACL(i) { u32x4 hq = hqc[24 + (i)]; \
  const u32x4* lp = WL + (long)(i) * 1024 + u; \
  u32x4 qi = lp[0], qf = lp[256], qg = lp[512], qo = lp[768]; \
  DOT4(ai, qi, hq); DOT4(af, qf, hq); DOT4(ag, qg, hq); DOT4(ao, qo, hq); }
    REP8(MACL)
#undef MACL
    float ig = sigmoidf_(ai), fg = sigmoidf_(af);
    float gg = tanhf_(ag), og = sigmoidf_(ao);
    c_reg = fg * c_reg + ig * gg;
    float h = og * tanhf_(c_reg);
    h_reg = h;
    hb[(cur ^ 1) * 256 + u] = f2h_bits(h);         // write NEXT buffer (no read conflict)
    int tcur = d ? (TCH - 1 - tt) : tt;
    Y[((long)b * yRowsPerB + t0 + tcur + yPad) * 512 + d * 256 + u] = f2bf(h);
    __syncthreads();                               // one barrier per step
  }
  if (r != NTCH - 1) {
    state[(chain * 2 + 0) * 256 + u] = h_reg;
    state[(chain * 2 + 1) * 256 + u] = c_reg;
  }
}

// ---------------- final conv (Cout=1): wave per row ----------------
__global__ __launch_bounds__(256) void conv4_kernel(
    const float* __restrict__ C3p, const float* __restrict__ w,
    const float* __restrict__ b2, float* __restrict__ out) {
  int row = blockIdx.x * 4 + (threadIdx.x >> 6);
  int lane = threadIdx.x & 63;
  int b = row >> 10, t = row & (N_ - 1);
  const float* a = C3p + ((long)b * NP + t) * 256;
  float acc = 0.f;
  for (int k = lane; k < 768; k += 64) acc += a[k] * w[k];
  for (int off = 32; off; off >>= 1) acc += __shfl_down(acc, off, 64);
  if (lane == 0) out[row] = acc + b2[0];
}

// ---------------- host launcher ----------------
extern "C" void kernel_launch(void* const* d_in, const int* in_sizes, int n_in,
                              void* d_out, int out_size, void* d_ws, size_t ws_size,
                              hipStream_t stream) {
  const float* dur     = (const float*)d_in[0];
  const int*   seq     = (const int*)d_in[1];
  const int*   order   = (const int*)d_in[2];
  const float* emb     = (const float*)d_in[3];
  const float* pos_emb = (const float*)d_in[4];
  const float* mix_w1  = (const float*)d_in[5];
  const float* mix_b1  = (const float*)d_in[6];
  const float* mix_w2  = (const float*)d_in[7];
  const float* mix_b2  = (const float*)d_in[8];
  const float* wih0    = (const float*)d_in[9];
  const float* whh0    = (const float*)d_in[10];
  const float* bih0    = (const float*)d_in[11];
  const float* bhh0    = (const float*)d_in[12];
  const float* wih1    = (const float*)d_in[13];
  const float* whh1    = (const float*)d_in[14];
  const float* bih1    = (const float*)d_in[15];
  const float* bhh1    = (const float*)d_in[16];
  const float* cnn_w1  = (const float*)d_in[17];
  const float* cnn_b1  = (const float*)d_in[18];
  const float* cnn_w2  = (const float*)d_in[19];
  const float* cnn_b2  = (const float*)d_in[20];
  float* out = (float*)d_out;
  float* ws = (float*)d_ws;

  (void)hipFuncSetAttribute((const void*)lstm_rec2_kernel,
                            hipFuncAttributeMaxDynamicSharedMemorySize, REC_LDS_BYTES);

  // ---- workspace layout (float units, 16-aligned) ----
  const long X0B_F = (long)GB * PP * X0S / 2;   // bf16 halves
  const long X1B_F = (long)GB * PP * 256 / 2;
  const long X2B_F = X1B_F;
  const long Z_E   = 2L * B_ * TCH * 1024;
  const long C3P_E = (long)B_ * NP * 256;
  long region = X0B_F + X1B_F + X2B_F;
  if (Z_E > region) region = Z_E;
  if (C3P_E > region) region = C3P_E;

  long off = 0;
  auto alloc = [&](long n) { long ret = off; off += (n + 15) & ~15L; return ret; };
  long o_region = alloc(region);
  long o_enc    = alloc((long)B_ * N_ * ENCS / 2);
  long o_Y0     = alloc((long)B_ * N_ * 512 / 2);
  long o_Y1p    = alloc((long)B_ * NP * 512 / 2);
  long o_W1h    = alloc(256L * 832 / 2);
  long o_W2h    = alloc(256L * 768 / 2);
  long o_Wc1h   = alloc(256L * 1536 / 2);
  long o_Wc1l   = alloc(256L * 1536 / 2);
  long o_Wc2r   = alloc(768);
  long o_Wih0h  = alloc(2L * 1024 * ENCS / 2);
  long o_Wih0l  = alloc(2L * 1024 * ENCS / 2);
  long o_Wih1h  = alloc(2L * 1024 * 512 / 2);
  long o_Wih1l  = alloc(2L * 1024 * 512 / 2);
  long o_Wv0    = alloc(49152L * 4);
  long o_Ws0    = alloc(16384L * 4);
  long o_Wv1    = alloc(49152L * 4);
  long o_Ws1    = alloc(16384L * 4);
  long o_bs0    = alloc(2048);
  long o_bs1    = alloc(2048);
  long o_state  = alloc(64L * 2 * 256);
  long o_nst    = alloc((long)B_ * N_);
  long o_nln    = alloc((long)B_ * N_);

  if ((size_t)(off * 4) > ws_size) {
    float v = -(1000.0f + (float)(ws_size >> 20));
    fill_sentinel_kernel<<<(out_size + 255) / 256, 256, 0, stream>>>(out, out_size, v);
    return;
  }

  u16*   X0b  = (u16*)(ws + o_region);
  u16*   X1b  = (u16*)(ws + o_region + X0B_F);
  u16*   X2b  = (u16*)(ws + o_region + X0B_F + X1B_F);
  float* Z    = ws + o_region;              // alias (after phase A)
  float* C3p  = ws + o_region;              // alias (after recs)
  u16*   enc  = (u16*)(ws + o_enc);
  u16*   Y0   = (u16*)(ws + o_Y0);
  u16*   Y1p  = (u16*)(ws + o_Y1p);
  u16*   W1h  = (u16*)(ws + o_W1h);
  u16*   W2h  = (u16*)(ws + o_W2h);
  u16*   Wc1h = (u16*)(ws + o_Wc1h);
  u16*   Wc1l = (u16*)(ws + o_Wc1l);
  float* Wc2r = ws + o_Wc2r;
  u16*   Wih0h = (u16*)(ws + o_Wih0h);
  u16*   Wih0l = (u16*)(ws + o_Wih0l);
  u16*   Wih1h = (u16*)(ws + o_Wih1h);
  u16*   Wih1l = (u16*)(ws + o_Wih1l);
  uint4* Wv0  = (uint4*)(ws + o_Wv0);
  uint4* Ws0  = (uint4*)(ws + o_Ws0);
  uint4* Wv1  = (uint4*)(ws + o_Wv1);
  uint4* Ws1  = (uint4*)(ws + o_Ws1);
  float* bs0  = ws + o_bs0;
  float* bs1  = ws + o_bs1;
  float* state = ws + o_state;
  int* nstart = (int*)(ws + o_nst);
  int* nlen   = (int*)(ws + o_nln);

  // ---- repacks / setup ----
  zero_bf_guards_kernel<<<GB, 256, 0, stream>>>(X0b, X1b);
  zero_y1p_guards_kernel<<<B_, 256, 0, stream>>>(Y1p);
  repack_conv_bt_kernel<<<(int)((256L * 832 + 255) / 256), 256, 0, stream>>>(
      mix_w1, W1h, nullptr, 266, X0S, 832, 256);
  repack_conv_bt_kernel<<<(int)((256L * 768 + 255) / 256), 256, 0, stream>>>(
      mix_w2, W2h, nullptr, 256, 256, 768, 256);
  repack_conv_bt_kernel<<<(int)((256L * 1536 + 255) / 256), 256, 0, stream>>>(
      cnn_w1, Wc1h, Wc1l, 512, 512, 1536, 256);
  repack_conv4_w_kernel<<<3, 256, 0, stream>>>(cnn_w2, Wc2r);
  for (int d = 0; d < 2; d++) {
    repack_dense_bt_kernel<<<(int)((1024L * ENCS + 255) / 256), 256, 0, stream>>>(
        wih0 + (long)d * 1024 * 258, Wih0h + (long)d * 1024 * ENCS,
        Wih0l + (long)d * 1024 * ENCS, 258, ENCS);
    repack_dense_bt_kernel<<<(int)((1024L * 512 + 255) / 256), 256, 0, stream>>>(
        wih1 + (long)d * 1024 * 512, Wih1h + (long)d * 1024 * 512,
        Wih1l + (long)d * 1024 * 512, 512, 512);
  }
  repack_whh_reg_kernel<<<192, 256, 0, stream>>>(whh0, Wv0);
  repack_whh_lds_kernel<<<64, 256, 0, stream>>>(whh0, Ws0);
  repack_whh_reg_kernel<<<192, 256, 0, stream>>>(whh1, Wv1);
  repack_whh_lds_kernel<<<64, 256, 0, stream>>>(whh1, Ws1);
  bias_sum_perm_kernel<<<8, 256, 0, stream>>>(bih0, bhh0, bs0);
  bias_sum_perm_kernel<<<8, 256, 0, stream>>>(bih1, bhh1, bs1);
  seg_scan_kernel<<<B_, 256, 0, stream>>>(seq, nstart, nlen);

  // ---- phase A: embed -> conv1 -> conv2 -> aggregate (8-batch chunks) ----
  for (int ch = 0; ch < NCHK; ch++) {
    int b0 = ch * GB;
    long total = (long)GB * P_ * X0S;
    embed_bf16_kernel<<<(int)((total + 255) / 256), 256, 0, stream>>>(seq, order, emb, pos_emb, X0b, b0);
    gemm_mfma_kernel<u16, false><<<dim3(GB * P_ / 64, 4), 256, 0, stream>>>(
        X0b, W1h, nullptr, mix_b1, X1b + 256,
        256, 832, P_, (long)PP * X0S, X0S, (long)PP * 256, 256, 1);
    gemm_mfma_kernel<u16, false><<<dim3(GB * P_ / 64, 4), 256, 0, stream>>>(
        X1b, W2h, nullptr, mix_b2, X2b + 256,
        256, 768, P_, (long)PP * 256, 256, (long)PP * 256, 256, 0);
    agg_enc_kernel<<<dim3(N_, GB), 256, 0, stream>>>(X2b, nstart, nlen, dur, enc, b0);
  }

  // ---- LSTM layers (time-chunked Z: MFMA x-proj + CU-resident rec) ----
  const long ZD = (long)B_ * TCH * 1024;
  for (int layer = 0; layer < 2; layer++) {
    const u16*  Xl   = (layer == 0) ? enc : Y0;
    int         Kp   = (layer == 0) ? ENCS : 512;
    const u16*  Wh   = (layer == 0) ? Wih0h : Wih1h;
    const u16*  Wl   = (layer == 0) ? Wih0l : Wih1l;
    long        WihD = (long)1024 * Kp;
    const float* bsl = (layer == 0) ? bs0 : bs1;
    const u32x4* Wv  = (const u32x4*)((layer == 0) ? Wv0 : Wv1);
    const u32x4* Wsp = (const u32x4*)((layer == 0) ? Ws0 : Ws1);
    u16*        Yl   = (layer == 0) ? Y0 : Y1p;
    int         yRows = (layer == 0) ? N_ : NP;
    int         yPad  = (layer == 0) ? 0 : 1;
    for (int r = 0; r < NTCH; r++) {
      for (int d = 0; d < 2; d++) {
        int t0 = (d == 0) ? r * TCH : (NTCH - 1 - r) * TCH;
        gemm_mfma_kernel<float, true><<<dim3(B_ * TCH / 64, 16), 256, 0, stream>>>(
            Xl + (long)t0 * Kp, Wh + (long)d * WihD, Wl + (long)d * WihD,
            bsl + d * 1024, Z + d * ZD,
            1024, Kp, TCH, (long)N_ * Kp, Kp, (long)TCH * 1024, 1024, 0);
      }
      lstm_rec2_kernel<<<64, 256, REC_LDS_BYTES, stream>>>(Z, Wv, Wsp, state, Yl, yRows, yPad, r);
    }
  }

  // ---- head: MFMA conv(relu) K=1536 (split weights), then 1-channel conv ----
  zero_c3p_guards_kernel<<<B_, 256, 0, stream>>>(C3p);
  gemm_mfma_kernel<float, true><<<dim3(B_ * N_ / 64, 4), 256, 0, stream>>>(
      Y1p, Wc1h, Wc1l, cnn_b1, C3p + 256,
      256, 1536, N_, (long)NP * 512, 512, (long)NP * 256, 256, 1);
  conv4_kernel<<<B_ * N_ / 4, 256, 0, stream>>>(C3p, Wc2r, cnn_b2, out);
}

// Round 10
// 5401.605 us; speedup vs baseline: 1.8003x; 1.8003x over previous
//
#include <hip/hip_runtime.h>
#include <math.h>

#define B_    32
#define P_    4096
#define N_    1024
#define POS_  10
#define PP    (P_ + 2)     // padded phoneme rows (guard top/bottom)
#define NP    (N_ + 2)     // padded note rows
#define GB    8            // batches per phase-A chunk
#define NCHK  (B_ / GB)    // 4 phase-A chunks
#define TCH   128          // LSTM time chunk (halved: Z ping-pong fits old footprint)
#define NTCH  (N_ / TCH)   // 8 time chunks
#define X0S   280          // X0b row stride (bf16): K_conv1 = 2*280+272 = 832 (mult of 32)
#define ENCS  288          // enc row stride (bf16): K mult of 32

typedef unsigned short u16;
typedef _Float16 h2_t __attribute__((ext_vector_type(2)));
typedef unsigned u32x4 __attribute__((ext_vector_type(4)));
typedef short s16x8 __attribute__((ext_vector_type(8)));     // 8 bf16 (4 VGPRs)
typedef float f32x4 __attribute__((ext_vector_type(4)));     // MFMA acc

// ---------------- helpers ----------------
__device__ __forceinline__ float sigmoidf_(float x) { return 1.f / (1.f + __expf(-x)); }
__device__ __forceinline__ float tanhf_(float x) {
  float t = fminf(fmaxf(x, -30.f), 30.f);
  float e = __expf(2.f * t);
  return (e - 1.f) / (e + 1.f);
}
__device__ __forceinline__ float bf2f(u16 u) { return __uint_as_float(((unsigned)u) << 16); }
__device__ __forceinline__ u16 f2bf(float f) {
  unsigned u = __float_as_uint(f);
  unsigned r = u + 0x7FFFu + ((u >> 16) & 1u);
  return (u16)(r >> 16);
}
__device__ __forceinline__ u16 f2h_bits(float x) {
  _Float16 hh = (_Float16)x; u16 u; __builtin_memcpy(&u, &hh, 2); return u;
}
__device__ __forceinline__ unsigned pack2h(float lo, float hi) {
  return (unsigned)f2h_bits(lo) | ((unsigned)f2h_bits(hi) << 16);
}
__device__ __forceinline__ float dot2(unsigned w, unsigned h, float acc) {
  return __builtin_amdgcn_fdot2(__builtin_bit_cast(h2_t, w), __builtin_bit_cast(h2_t, h), acc, false);
}
#define DOT4(acc, wq, hq) \
  acc = dot2((wq).x, (hq).x, acc); acc = dot2((wq).y, (hq).y, acc); \
  acc = dot2((wq).z, (hq).z, acc); acc = dot2((wq).w, (hq).w, acc);

#define REP24(X) X(0)X(1)X(2)X(3)X(4)X(5)X(6)X(7)X(8)X(9)X(10)X(11)X(12)X(13)X(14)X(15)X(16)X(17)X(18)X(19)X(20)X(21)X(22)X(23)
#define REP8(X)  X(0)X(1)X(2)X(3)X(4)X(5)X(6)X(7)

__device__ __forceinline__ void stc(float* p, float v) { *p = v; }
__device__ __forceinline__ void stc(u16* p, float v)   { *p = f2bf(v); }

// ---------------- diagnostics ----------------
__global__ void fill_sentinel_kernel(float* out, int n, float v) {
  int i = blockIdx.x * 256 + threadIdx.x;
  if (i < n) out[i] = v;
}

// ---------------- zero guards ----------------
__global__ void zero_bf_guards_kernel(u16* X0b, u16* X1b) {
  int cb = blockIdx.x, t = threadIdx.x;
  for (int c = t; c < X0S; c += 256) {
    X0b[((long)cb * PP + 0) * X0S + c] = 0;
    X0b[((long)cb * PP + PP - 1) * X0S + c] = 0;
  }
  if (t < 256) {
    X1b[((long)cb * PP + 0) * 256 + t] = 0;
    X1b[((long)cb * PP + PP - 1) * 256 + t] = 0;
  }
}
__global__ void zero_y1p_guards_kernel(u16* Y1p) {
  int b = blockIdx.x, t = threadIdx.x;
  for (int c = t; c < 512; c += 256) {
    Y1p[((long)b * NP + 0) * 512 + c] = 0;
    Y1p[((long)b * NP + NP - 1) * 512 + c] = 0;
  }
}
__global__ void zero_c3p_guards_kernel(float* C3p) {
  int b = blockIdx.x, t = threadIdx.x;
  if (t < 256) {
    C3p[((long)b * NP + 0) * 256 + t] = 0.f;
    C3p[((long)b * NP + NP - 1) * 256 + t] = 0.f;
  }
}

// ---------------- embedding (chunked, bf16 out, stride 280) ----------------
__global__ void embed_bf16_kernel(const int* __restrict__ seq, const int* __restrict__ order,
                                  const float* __restrict__ emb, const float* __restrict__ pos_emb,
                                  u16* __restrict__ X0b, int b0) {
  long i = (long)blockIdx.x * 256 + threadIdx.x;
  const long total = (long)GB * P_ * X0S;
  if (i >= total) return;
  int c = (int)(i % X0S);
  long bp = i / X0S;
  int p = (int)(bp % P_);
  int cb = (int)(bp / P_);
  int b = b0 + cb;
  float v = 0.f;
  if (c < 256)      v = emb[(long)seq[(long)b * P_ + p] * 256 + c];
  else if (c < 266) v = pos_emb[(long)order[(long)b * P_ + p] * POS_ + (c - 256)];
  X0b[((long)cb * PP + p + 1) * X0S + c] = f2bf(v);
}

// ---------------- weight repacks ----------------
__global__ void repack_conv_bt_kernel(const float* __restrict__ w, u16* __restrict__ hi,
                                      u16* __restrict__ lo, int CinReal, int strideA,
                                      int Kpad, int Cout) {
  long i = (long)blockIdx.x * 256 + threadIdx.x;
  if (i >= (long)Cout * Kpad) return;
  int co = (int)(i / Kpad), k = (int)(i - (long)co * Kpad);
  int r = k / strideA, ci = k - r * strideA;
  float v = (r < 3 && ci < CinReal) ? w[((long)co * CinReal + ci) * 3 + r] : 0.f;
  u16 h = f2bf(v);
  hi[i] = h;
  if (lo) lo[i] = f2bf(v - bf2f(h));
}
__global__ void repack_dense_bt_kernel(const float* __restrict__ w, u16* __restrict__ hi,
                                       u16* __restrict__ lo, int CinReal, int Kpad) {
  long i = (long)blockIdx.x * 256 + threadIdx.x;
  if (i >= 1024L * Kpad) return;
  int j = (int)(i / Kpad), k = (int)(i - (long)j * Kpad);
  int co = (j & 3) * 256 + (j >> 2);
  float v = (k < CinReal) ? w[(long)co * CinReal + k] : 0.f;
  u16 h = f2bf(v);
  hi[i] = h;
  lo[i] = f2bf(v - bf2f(h));
}
// Whh k<192 slice -> register-resident quads (round-8 layout):
// Wv[((d*2+rb)*24+kq)*512 + j]; row(j,rb): R = (j&3)*256 + (j>>2) + rb*128
__global__ void repack_whh_reg_kernel(const float* __restrict__ whh, uint4* __restrict__ Wv) {
  long i = (long)blockIdx.x * 256 + threadIdx.x;
  if (i >= 49152) return;
  int j = (int)(i & 511);
  int t = (int)(i >> 9);
  int kq = t % 24, rb = (t / 24) & 1, d = t / 48;
  int R = (j & 3) * 256 + (j >> 2) + rb * 128;
  const float* wr = whh + ((long)d * 1024 + R) * 256;
  uint4 o; unsigned* op = (unsigned*)&o;
#pragma unroll
  for (int q = 0; q < 4; q++) {
    int k = kq * 8 + 2 * q;
    op[q] = pack2h(wr[k], wr[k + 1]);
  }
  Wv[i] = o;
}
// Whh k in [192,256) -> LDS-resident, lane-linear (round-8 layout):
// Ws[d*8192 + rb*4096 + i2*512 + j]
__global__ void repack_whh_lds_kernel(const float* __restrict__ whh, uint4* __restrict__ Ws) {
  long i = (long)blockIdx.x * 256 + threadIdx.x;
  if (i >= 16384) return;
  int d = (int)(i >> 13);
  int a = (int)(i & 8191);
  int rb = a >> 12;
  int rem = a & 4095;
  int i2 = rem >> 9, j = rem & 511;
  int R = (j & 3) * 256 + (j >> 2) + rb * 128;
  const float* wr = whh + ((long)d * 1024 + R) * 256;
  uint4 o; unsigned* op = (unsigned*)&o;
#pragma unroll
  for (int q = 0; q < 4; q++) {
    int k = 192 + i2 * 8 + 2 * q;
    op[q] = pack2h(wr[k], wr[k + 1]);
  }
  Ws[i] = o;
}
__global__ void bias_sum_perm_kernel(const float* __restrict__ a, const float* __restrict__ b,
                                     float* __restrict__ dst) {
  int i = blockIdx.x * 256 + threadIdx.x;
  if (i >= 2048) return;
  int d = i >> 10, j = i & 1023;
  int R = (j & 3) * 256 + (j >> 2);
  dst[i] = a[d * 1024 + R] + b[d * 1024 + R];
}
__global__ void repack_conv4_w_kernel(const float* __restrict__ w, float* __restrict__ dst) {
  int i = blockIdx.x * 256 + threadIdx.x;
  if (i < 768) { int r = i >> 8, ci = i & 255; dst[i] = w[ci * 3 + r]; }
}

// ---------------- MFMA GEMM tile body (shared by standalone + fused) ----------------
template <typename CT, bool SPLIT>
__device__ __forceinline__ void gemm_tile(
    int wave, int lane, int bx, int by,
    const u16* __restrict__ A, const u16* __restrict__ Bt, const u16* __restrict__ Bt2,
    const float* __restrict__ bias, CT* __restrict__ C,
    int N, int Kpad, int Mb,
    long aBatchStride, int aRowStride,
    long cBatchStride, int cRowStride, int relu) {
  int lrow = lane & 15, lk = (lane >> 4) * 8;
  int row0 = bx * 64 + wave * 16;
  int col0 = by * 64;
  int grow = row0 + lrow;
  int b_ = grow / Mb, m_ = grow - b_ * Mb;
  const u16* arow = A + (long)b_ * aBatchStride + (long)m_ * aRowStride + lk;
  const u16* bp0 = Bt + (long)(col0 + lrow) * Kpad + lk;
  const u16* bq0 = SPLIT ? (Bt2 + (long)(col0 + lrow) * Kpad + lk) : bp0;
  f32x4 acc0 = {0.f, 0.f, 0.f, 0.f};
  f32x4 acc1 = acc0, acc2 = acc0, acc3 = acc0;
  for (int kk = 0; kk < Kpad; kk += 32) {
    s16x8 av = *(const s16x8*)(arow + kk);
    acc0 = __builtin_amdgcn_mfma_f32_16x16x32_bf16(av, *(const s16x8*)(bp0 + kk), acc0, 0, 0, 0);
    acc1 = __builtin_amdgcn_mfma_f32_16x16x32_bf16(av, *(const s16x8*)(bp0 + 16L * Kpad + kk), acc1, 0, 0, 0);
    acc2 = __builtin_amdgcn_mfma_f32_16x16x32_bf16(av, *(const s16x8*)(bp0 + 32L * Kpad + kk), acc2, 0, 0, 0);
    acc3 = __builtin_amdgcn_mfma_f32_16x16x32_bf16(av, *(const s16x8*)(bp0 + 48L * Kpad + kk), acc3, 0, 0, 0);
    if (SPLIT) {
      acc0 = __builtin_amdgcn_mfma_f32_16x16x32_bf16(av, *(const s16x8*)(bq0 + kk), acc0, 0, 0, 0);
      acc1 = __builtin_amdgcn_mfma_f32_16x16x32_bf16(av, *(const s16x8*)(bq0 + 16L * Kpad + kk), acc1, 0, 0, 0);
      acc2 = __builtin_amdgcn_mfma_f32_16x16x32_bf16(av, *(const s16x8*)(bq0 + 32L * Kpad + kk), acc2, 0, 0, 0);
      acc3 = __builtin_amdgcn_mfma_f32_16x16x32_bf16(av, *(const s16x8*)(bq0 + 48L * Kpad + kk), acc3, 0, 0, 0);
    }
  }
  int erow = row0 + (lane >> 4) * 4;
  int b2 = erow / Mb, m2 = erow - b2 * Mb;
  CT* cbase = C + (long)b2 * cBatchStride + (long)m2 * cRowStride + col0 + lrow;
#define EPI(cc, accv) { \
    float bv = bias[col0 + (cc) * 16 + lrow]; \
    float v0 = accv[0] + bv, v1 = accv[1] + bv, v2 = accv[2] + bv, v3 = accv[3] + bv; \
    if (relu) { v0 = fmaxf(v0, 0.f); v1 = fmaxf(v1, 0.f); v2 = fmaxf(v2, 0.f); v3 = fmaxf(v3, 0.f); } \
    stc(cbase + 0L * cRowStride + (cc) * 16, v0); \
    stc(cbase + 1L * cRowStride + (cc) * 16, v1); \
    stc(cbase + 2L * cRowStride + (cc) * 16, v2); \
    stc(cbase + 3L * cRowStride + (cc) * 16, v3); }
  EPI(0, acc0) EPI(1, acc1) EPI(2, acc2) EPI(3, acc3)
#undef EPI
}

template <typename CT, bool SPLIT>
__global__ __launch_bounds__(256) void gemm_mfma_kernel(
    const u16* __restrict__ A, const u16* __restrict__ Bt, const u16* __restrict__ Bt2,
    const float* __restrict__ bias, CT* __restrict__ C,
    int N, int Kpad, int Mb,
    long aBatchStride, int aRowStride,
    long cBatchStride, int cRowStride, int relu) {
  int tid = threadIdx.x;
  gemm_tile<CT, SPLIT>(tid >> 6, tid & 63, blockIdx.x, blockIdx.y,
                       A, Bt, Bt2, bias, C, N, Kpad, Mb,
                       aBatchStride, aRowStride, cBatchStride, cRowStride, relu);
}

// ---------------- note-segment scan: parallel runs-scan ----------------
__global__ __launch_bounds__(256) void seg_scan_kernel(const int* __restrict__ seq,
                                int* __restrict__ nstart, int* __restrict__ nlen) {
  __shared__ unsigned char v[P_];
  __shared__ int sc[2][256];
  int b = blockIdx.x, tid = threadIdx.x;
  for (int i = tid; i < P_; i += 256) {
    int s = seq[(long)b * P_ + i];
    v[i] = (s > 1 && i != P_ - 1) ? 1 : 0;   // last position never included
  }
  for (int n = tid; n < N_; n += 256) { nstart[b * N_ + n] = 0; nlen[b * N_ + n] = 0; }
  __syncthreads();
  int base = tid << 4;
  int c = 0;
#pragma unroll
  for (int i = 0; i < 16; i++) {
    int p = base + i;
    int val = v[p];
    int prev = p ? v[p - 1] : 0;
    c += val & (prev ^ 1);
  }
  sc[0][tid] = c;
  __syncthreads();
  int cur = 0;
  for (int d = 1; d < 256; d <<= 1) {
    int x = sc[cur][tid];
    if (tid >= d) x += sc[cur][tid - d];
    sc[cur ^ 1][tid] = x;
    cur ^= 1;
    __syncthreads();
  }
  int sg = tid ? sc[cur][tid - 1] : 0;
  for (int i = 0; i < 16; i++) {
    int p = base + i;
    int val = v[p];
    int prev = p ? v[p - 1] : 0;
    if (val && !prev) {
      if (sg < N_) {
        int len = 0, q = p;
        while (q < P_ && v[q]) { len++; q++; }
        nstart[b * N_ + sg] = p;
        nlen[b * N_ + sg] = len;
      }
      sg++;
    }
  }
}

// ---------------- segment mean + enc (bf16 in/out, stride 288) ----------------
__global__ __launch_bounds__(256) void agg_enc_kernel(
    const u16* __restrict__ X2b, const int* __restrict__ nstart, const int* __restrict__ nlen,
    const float* __restrict__ dur, u16* __restrict__ enc, int b0) {
  int n = blockIdx.x, gb = blockIdx.y;
  int b = b0 + gb;
  int d = threadIdx.x;
  int len = nlen[b * N_ + n], st = nstart[b * N_ + n];
  float acc = 0.f;
  for (int i = 0; i < len; i++) acc += bf2f(X2b[((long)gb * PP + st + 1 + i) * 256 + d]);
  float m = (len > 0) ? acc / (float)len : 0.f;
  long e = ((long)b * N_ + n) * ENCS;
  enc[e + d] = f2bf(m);
  if (d == 0) {
    float dd = dur[b * N_ + n];
    enc[e + 256] = f2bf(dd);
    enc[e + 257] = f2bf(1.f / (dd + 1.f));
  }
  if (d >= 2 && d < 32) enc[e + 256 + d] = 0;  // zero tail 258..287
}

// ---------------- FUSED kernel: rec (blocks 0..63) + next-chunk x-proj GEMM ----------------
// Rec body = round-8 form verbatim (best measured: 1.85us/step). Gemm blocks run the
// proven MFMA tile body on the OTHER 192 CUs, writing chunk rq's Z into the ping-pong
// buffer. No shared state between roles; 136KB dynamic LDS forces 1 WG/CU.
#define REC_LDS_BYTES (131072 + 4096 + 1024)
__global__ __attribute__((amdgpu_waves_per_eu(2, 2))) __launch_bounds__(512)
void rec_gemm_kernel(
    // rec args
    const float* __restrict__ Z,      // [2][32][TCH][1024] fp32, permuted cols
    const u32x4* __restrict__ Wv,     // [2][2][24][512] fp16 quads (k<192)
    const u32x4* __restrict__ Ws,     // [2][2][8][512] fp16 quads (k>=192)
    float* __restrict__ state,        // [64][2][256]
    u16* __restrict__ Y, int yRowsPerB, int yPad, int r,
    // gemm args (chunk rq -> Zg)
    const u16* __restrict__ Xg, const u16* __restrict__ Whg, const u16* __restrict__ Wlg,
    const float* __restrict__ bsg, float* __restrict__ Zg, int Kpg, int rq) {
  int tid = threadIdx.x;
  if (blockIdx.x >= 64) {
    // ---- GEMM role: two 64x64 tiles per 512-thread WG ----
    int half = tid >> 8, vt = tid & 255;
    int tile = (blockIdx.x - 64) * 2 + half;     // [0, 2048)
    int dir = tile >> 10;
    int t2 = tile & 1023;
    int bx = t2 & 63, by = t2 >> 6;
    int t0g = (dir == 0) ? rq * TCH : (NTCH - 1 - rq) * TCH;
    long WihD = (long)1024 * Kpg;
    long ZD = (long)B_ * TCH * 1024;
    gemm_tile<float, true>((vt >> 6), vt & 63, bx, by,
        Xg + (long)t0g * Kpg, Whg + (long)dir * WihD, Wlg + (long)dir * WihD,
        bsg + dir * 1024, Zg + (long)dir * ZD,
        1024, Kpg, TCH, (long)N_ * Kpg, Kpg, (long)TCH * 1024, 1024, 0);
    return;
  }
  // ---- REC role (round-8 body) ----
  extern __shared__ char smem[];
  u32x4* WL = (u32x4*)smem;                              // 8192 quads
  float* zb = (float*)(smem + 131072);                   // 1024 f32
  u16*   hb = (u16*)(smem + 131072 + 4096);              // 256 fp16
  const u32x4* hb4 = (const u32x4*)hb;                   // 32 quads

  int chain = blockIdx.x;
  int d = chain >> 5, b = chain & 31;
  const float* Zb = Z + (long)(d * 32 + b) * (TCH * 1024);

  for (int iq = 0; iq < 16; ++iq) {
    int q = iq * 512 + tid;
    WL[q] = Ws[(long)d * 8192 + q];
  }
  const u32x4* WvD = Wv + (long)d * 2 * 24 * 512;
#define DECLW(i) u32x4 wA##i, wB##i;
  REP24(DECLW)
#undef DECLW
#define LOADW(i) wA##i = WvD[(i) * 512 + tid]; wB##i = WvD[(24 + (i)) * 512 + tid];
  REP24(LOADW)
#undef LOADW
#define PINW(i) asm volatile("" : "+v"(wA##i), "+v"(wB##i));
  REP24(PINW)
#undef PINW

  float h_reg = 0.f, c_reg = 0.f;
  if (tid < 256) {
    if (r > 0) {
      h_reg = state[(chain * 2 + 0) * 256 + tid];
      c_reg = state[(chain * 2 + 1) * 256 + tid];
    }
    hb[tid] = f2h_bits(h_reg);
  }
  __syncthreads();

  int t0 = (d == 0) ? r * TCH : (NTCH - 1 - r) * TCH;
  int tcf = d ? (TCH - 1) : 0;
  float preA = Zb[(long)tcf * 1024 + tid];
  float preB = Zb[(long)tcf * 1024 + 512 + tid];

  for (int tt = 0; tt < TCH; ++tt) {
    float accA = preA, accB = preB;
    if (tt + 1 < TCH) {
      int tc2 = d ? (TCH - 2 - tt) : (tt + 1);
      preA = Zb[(long)tc2 * 1024 + tid];
      preB = Zb[(long)tc2 * 1024 + 512 + tid];
    }
#define MACW(i) { u32x4 hq = hb4[i]; DOT4(accA, wA##i, hq); DOT4(accB, wB##i, hq); }
    REP24(MACW)
#undef MACW
#define MACL(i) { u32x4 hq = hb4[24 + (i)]; \
                  u32x4 qa = WL[(i) * 512 + tid]; \
                  u32x4 qb = WL[4096 + (i) * 512 + tid]; \
                  DOT4(accA, qa, hq); DOT4(accB, qb, hq); }
    REP8(MACL)
#undef MACL
    zb[tid] = accA;
    zb[tid + 512] = accB;
    __syncthreads();
    int tcur = d ? (TCH - 1 - tt) : tt;
    if (tid < 256) {
      float4 z4 = *(const float4*)&zb[tid * 4];   // (i,f,g,o) of unit tid
      float ig = sigmoidf_(z4.x), fg = sigmoidf_(z4.y);
      float gg = tanhf_(z4.z), og = sigmoidf_(z4.w);
      c_reg = fg * c_reg + ig * gg;
      float h = og * tanhf_(c_reg);
      h_reg = h;
      hb[tid] = f2h_bits(h);
      Y[((long)b * yRowsPerB + t0 + tcur + yPad) * 512 + d * 256 + tid] = f2bf(h);
    }
    __syncthreads();
  }
  if (r != NTCH - 1 && tid < 256) {
    state[(chain * 2 + 0) * 256 + tid] = h_reg;
    state[(chain * 2 + 1) * 256 + tid] = c_reg;
  }
}

// ---------------- final conv (Cout=1): wave per row ----------------
__global__ __launch_bounds__(256) void conv4_kernel(
    const float* __restrict__ C3p, const float* __restrict__ w,
    const float* __restrict__ b2, float* __restrict__ out) {
  int row = blockIdx.x * 4 + (threadIdx.x >> 6);
  int lane = threadIdx.x & 63;
  int b = row >> 10, t = row & (N_ - 1);
  const float* a = C3p + ((long)b * NP + t) * 256;
  float acc = 0.f;
  for (int k = lane; k < 768; k += 64) acc += a[k] * w[k];
  for (int off = 32; off; off >>= 1) acc += __shfl_down(acc, off, 64);
  if (lane == 0) out[row] = acc + b2[0];
}

// ---------------- host launcher ----------------
extern "C" void kernel_launch(void* const* d_in, const int* in_sizes, int n_in,
                              void* d_out, int out_size, void* d_ws, size_t ws_size,
                              hipStream_t stream) {
  const float* dur     = (const float*)d_in[0];
  const int*   seq     = (const int*)d_in[1];
  const int*   order   = (const int*)d_in[2];
  const float* emb     = (const float*)d_in[3];
  const float* pos_emb = (const float*)d_in[4];
  const float* mix_w1  = (const float*)d_in[5];
  const float* mix_b1  = (const float*)d_in[6];
  const float* mix_w2  = (const float*)d_in[7];
  const float* mix_b2  = (const float*)d_in[8];
  const float* wih0    = (const float*)d_in[9];
  const float* whh0    = (const float*)d_in[10];
  const float* bih0    = (const float*)d_in[11];
  const float* bhh0    = (const float*)d_in[12];
  const float* wih1    = (const float*)d_in[13];
  const float* whh1    = (const float*)d_in[14];
  const float* bih1    = (const float*)d_in[15];
  const float* bhh1    = (const float*)d_in[16];
  const float* cnn_w1  = (const float*)d_in[17];
  const float* cnn_b1  = (const float*)d_in[18];
  const float* cnn_w2  = (const float*)d_in[19];
  const float* cnn_b2  = (const float*)d_in[20];
  float* out = (float*)d_out;
  float* ws = (float*)d_ws;

  (void)hipFuncSetAttribute((const void*)rec_gemm_kernel,
                            hipFuncAttributeMaxDynamicSharedMemorySize, REC_LDS_BYTES);

  // ---- workspace layout (float units, 16-aligned) ----
  const long X0B_F = (long)GB * PP * X0S / 2;   // bf16 halves
  const long X1B_F = (long)GB * PP * 256 / 2;
  const long X2B_F = X1B_F;
  const long ZE2   = 2L * B_ * TCH * 1024;      // one Z ping-pong buffer (both dirs)
  const long C3P_E = (long)B_ * NP * 256;
  long region = X0B_F + X1B_F + X2B_F;
  if (2 * ZE2 > region) region = 2 * ZE2;       // two Z buffers
  if (C3P_E > region) region = C3P_E;

  long off = 0;
  auto alloc = [&](long n) { long ret = off; off += (n + 15) & ~15L; return ret; };
  long o_region = alloc(region);
  long o_enc    = alloc((long)B_ * N_ * ENCS / 2);
  long o_Y0     = alloc((long)B_ * N_ * 512 / 2);
  long o_Y1p    = alloc((long)B_ * NP * 512 / 2);
  long o_W1h    = alloc(256L * 832 / 2);
  long o_W2h    = alloc(256L * 768 / 2);
  long o_Wc1h   = alloc(256L * 1536 / 2);
  long o_Wc1l   = alloc(256L * 1536 / 2);
  long o_Wc2r   = alloc(768);
  long o_Wih0h  = alloc(2L * 1024 * ENCS / 2);
  long o_Wih0l  = alloc(2L * 1024 * ENCS / 2);
  long o_Wih1h  = alloc(2L * 1024 * 512 / 2);
  long o_Wih1l  = alloc(2L * 1024 * 512 / 2);
  long o_Wv0    = alloc(49152L * 4);
  long o_Ws0    = alloc(16384L * 4);
  long o_Wv1    = alloc(49152L * 4);
  long o_Ws1    = alloc(16384L * 4);
  long o_bs0    = alloc(2048);
  long o_bs1    = alloc(2048);
  long o_state  = alloc(64L * 2 * 256);
  long o_nst    = alloc((long)B_ * N_);
  long o_nln    = alloc((long)B_ * N_);

  if ((size_t)(off * 4) > ws_size) {
    float v = -(1000.0f + (float)(ws_size >> 20));
    fill_sentinel_kernel<<<(out_size + 255) / 256, 256, 0, stream>>>(out, out_size, v);
    return;
  }

  u16*   X0b  = (u16*)(ws + o_region);
  u16*   X1b  = (u16*)(ws + o_region + X0B_F);
  u16*   X2b  = (u16*)(ws + o_region + X0B_F + X1B_F);
  float* Zbuf[2] = { ws + o_region, ws + o_region + ZE2 };   // alias (after phase A)
  float* C3p  = ws + o_region;              // alias (after recs)
  u16*   enc  = (u16*)(ws + o_enc);
  u16*   Y0   = (u16*)(ws + o_Y0);
  u16*   Y1p  = (u16*)(ws + o_Y1p);
  u16*   W1h  = (u16*)(ws + o_W1h);
  u16*   W2h  = (u16*)(ws + o_W2h);
  u16*   Wc1h = (u16*)(ws + o_Wc1h);
  u16*   Wc1l = (u16*)(ws + o_Wc1l);
  float* Wc2r = ws + o_Wc2r;
  u16*   Wih0h = (u16*)(ws + o_Wih0h);
  u16*   Wih0l = (u16*)(ws + o_Wih0l);
  u16*   Wih1h = (u16*)(ws + o_Wih1h);
  u16*   Wih1l = (u16*)(ws + o_Wih1l);
  uint4* Wv0  = (uint4*)(ws + o_Wv0);
  uint4* Ws0  = (uint4*)(ws + o_Ws0);
  uint4* Wv1  = (uint4*)(ws + o_Wv1);
  uint4* Ws1  = (uint4*)(ws + o_Ws1);
  float* bs0  = ws + o_bs0;
  float* bs1  = ws + o_bs1;
  float* state = ws + o_state;
  int* nstart = (int*)(ws + o_nst);
  int* nlen   = (int*)(ws + o_nln);

  // ---- repacks / setup ----
  zero_bf_guards_kernel<<<GB, 256, 0, stream>>>(X0b, X1b);
  zero_y1p_guards_kernel<<<B_, 256, 0, stream>>>(Y1p);
  repack_conv_bt_kernel<<<(int)((256L * 832 + 255) / 256), 256, 0, stream>>>(
      mix_w1, W1h, nullptr, 266, X0S, 832, 256);
  repack_conv_bt_kernel<<<(int)((256L * 768 + 255) / 256), 256, 0, stream>>>(
      mix_w2, W2h, nullptr, 256, 256, 768, 256);
  repack_conv_bt_kernel<<<(int)((256L * 1536 + 255) / 256), 256, 0, stream>>>(
      cnn_w1, Wc1h, Wc1l, 512, 512, 1536, 256);
  repack_conv4_w_kernel<<<3, 256, 0, stream>>>(cnn_w2, Wc2r);
  for (int d = 0; d < 2; d++) {
    repack_dense_bt_kernel<<<(int)((1024L * ENCS + 255) / 256), 256, 0, stream>>>(
        wih0 + (long)d * 1024 * 258, Wih0h + (long)d * 1024 * ENCS,
        Wih0l + (long)d * 1024 * ENCS, 258, ENCS);
    repack_dense_bt_kernel<<<(int)((1024L * 512 + 255) / 256), 256, 0, stream>>>(
        wih1 + (long)d * 1024 * 512, Wih1h + (long)d * 1024 * 512,
        Wih1l + (long)d * 1024 * 512, 512, 512);
  }
  repack_whh_reg_kernel<<<192, 256, 0, stream>>>(whh0, Wv0);
  repack_whh_lds_kernel<<<64, 256, 0, stream>>>(whh0, Ws0);
  repack_whh_reg_kernel<<<192, 256, 0, stream>>>(whh1, Wv1);
  repack_whh_lds_kernel<<<64, 256, 0, stream>>>(whh1, Ws1);
  bias_sum_perm_kernel<<<8, 256, 0, stream>>>(bih0, bhh0, bs0);
  bias_sum_perm_kernel<<<8, 256, 0, stream>>>(bih1, bhh1, bs1);
  seg_scan_kernel<<<B_, 256, 0, stream>>>(seq, nstart, nlen);

  // ---- phase A: embed -> conv1 -> conv2 -> aggregate (8-batch chunks) ----
  for (int ch = 0; ch < NCHK; ch++) {
    int b0 = ch * GB;
    long total = (long)GB * P_ * X0S;
    embed_bf16_kernel<<<(int)((total + 255) / 256), 256, 0, stream>>>(seq, order, emb, pos_emb, X0b, b0);
    gemm_mfma_kernel<u16, false><<<dim3(GB * P_ / 64, 4), 256, 0, stream>>>(
        X0b, W1h, nullptr, mix_b1, X1b + 256,
        256, 832, P_, (long)PP * X0S, X0S, (long)PP * 256, 256, 1);
    gemm_mfma_kernel<u16, false><<<dim3(GB * P_ / 64, 4), 256, 0, stream>>>(
        X1b, W2h, nullptr, mix_b2, X2b + 256,
        256, 768, P_, (long)PP * 256, 256, (long)PP * 256, 256, 0);
    agg_enc_kernel<<<dim3(N_, GB), 256, 0, stream>>>(X2b, nstart, nlen, dur, enc, b0);
  }

  // ---- LSTM layers: prologue GEMM(chunk 0), then fused rec(r) + GEMM(r+1) ----
  const long ZD = (long)B_ * TCH * 1024;
  for (int layer = 0; layer < 2; layer++) {
    const u16*  Xl   = (layer == 0) ? enc : Y0;
    int         Kp   = (layer == 0) ? ENCS : 512;
    const u16*  Wh   = (layer == 0) ? Wih0h : Wih1h;
    const u16*  Wl   = (layer == 0) ? Wih0l : Wih1l;
    long        WihD = (long)1024 * Kp;
    const float* bsl = (layer == 0) ? bs0 : bs1;
    const u32x4* Wv  = (const u32x4*)((layer == 0) ? Wv0 : Wv1);
    const u32x4* Wsp = (const u32x4*)((layer == 0) ? Ws0 : Ws1);
    u16*        Yl   = (layer == 0) ? Y0 : Y1p;
    int         yRows = (layer == 0) ? N_ : NP;
    int         yPad  = (layer == 0) ? 0 : 1;
    // prologue: chunk 0 x-proj into Zbuf[0]
    for (int d = 0; d < 2; d++) {
      int t0 = (d == 0) ? 0 : (NTCH - 1) * TCH;
      gemm_mfma_kernel<float, true><<<dim3(B_ * TCH / 64, 16), 256, 0, stream>>>(
          Xl + (long)t0 * Kp, Wh + (long)d * WihD, Wl + (long)d * WihD,
          bsl + d * 1024, Zbuf[0] + d * ZD,
          1024, Kp, TCH, (long)N_ * Kp, Kp, (long)TCH * 1024, 1024, 0);
    }
    // fused: rec(r) on Zbuf[r&1]  ||  gemm(r+1) into Zbuf[(r+1)&1]
    for (int r = 0; r < NTCH; r++) {
      int gemmWGs = (r < NTCH - 1) ? 1024 : 0;   // 2048 tiles / 2 per WG
      rec_gemm_kernel<<<64 + gemmWGs, 512, REC_LDS_BYTES, stream>>>(
          Zbuf[r & 1], Wv, Wsp, state, Yl, yRows, yPad, r,
          Xl, Wh, Wl, bsl, Zbuf[(r + 1) & 1], Kp, r + 1);
    }
  }

  // ---- head: MFMA conv(relu) K=1536 (split weights), then 1-channel conv ----
  zero_c3p_guards_kernel<<<B_, 256, 0, stream>>>(C3p);
  gemm_mfma_kernel<float, true><<<dim3(B_ * N_ / 64, 4), 256, 0, stream>>>(
      Y1p, Wc1h, Wc1l, cnn_b1, C3p + 256,
      256, 1536, N_, (long)NP * 512, 512, (long)NP * 256, 256, 1);
  conv4_kernel<<<B_ * N_ / 4, 256, 0, stream>>>(C3p, Wc2r, cnn_b2, out);
}

// Round 12
// 4414.534 us; speedup vs baseline: 2.2028x; 1.2236x over previous
//
#include <hip/hip_runtime.h>
#include <math.h>

#define B_    32
#define P_    4096
#define N_    1024
#define POS_  10
#define PP    (P_ + 2)     // padded phoneme rows (guard top/bottom)
#define NP    (N_ + 2)     // padded note rows
#define GB    8            // batches per phase-A chunk
#define NCHK  (B_ / GB)    // 4 phase-A chunks
#define TCH   128          // LSTM time chunk (Z ping-pong fits old footprint)
#define NTCH  (N_ / TCH)   // 8 time chunks
#define X0S   280          // X0b row stride (bf16): K_conv1 = 2*280+272 = 832 (mult of 32)
#define ENCS  288          // enc row stride (bf16): K mult of 32
#define LROW  80           // LDS tile row stride in BYTES (64 data + 16 pad): bank-floor, no swizzle
#define LTILE (64 * LROW)  // 5120 B per [64][32]-bf16 buffer
#define GEMM_LDS (3 * LTILE)  // 15360 B per tile (A, Bhi, Blo)

typedef unsigned short u16;
typedef _Float16 h2_t __attribute__((ext_vector_type(2)));
typedef unsigned u32x4 __attribute__((ext_vector_type(4)));
typedef short s16x8 __attribute__((ext_vector_type(8)));     // 8 bf16 (4 VGPRs)
typedef float f32x4 __attribute__((ext_vector_type(4)));     // MFMA acc

// ---------------- helpers ----------------
__device__ __forceinline__ float sigmoidf_(float x) { return 1.f / (1.f + __expf(-x)); }
__device__ __forceinline__ float tanhf_(float x) {
  float t = fminf(fmaxf(x, -30.f), 30.f);
  float e = __expf(2.f * t);
  return (e - 1.f) / (e + 1.f);
}
__device__ __forceinline__ float bf2f(u16 u) { return __uint_as_float(((unsigned)u) << 16); }
__device__ __forceinline__ u16 f2bf(float f) {
  unsigned u = __float_as_uint(f);
  unsigned r = u + 0x7FFFu + ((u >> 16) & 1u);
  return (u16)(r >> 16);
}
__device__ __forceinline__ u16 f2h_bits(float x) {
  _Float16 hh = (_Float16)x; u16 u; __builtin_memcpy(&u, &hh, 2); return u;
}
__device__ __forceinline__ unsigned pack2h(float lo, float hi) {
  return (unsigned)f2h_bits(lo) | ((unsigned)f2h_bits(hi) << 16);
}
__device__ __forceinline__ float dot2(unsigned w, unsigned h, float acc) {
  return __builtin_amdgcn_fdot2(__builtin_bit_cast(h2_t, w), __builtin_bit_cast(h2_t, h), acc, false);
}
#define DOT4(acc, wq, hq) \
  acc = dot2((wq).x, (hq).x, acc); acc = dot2((wq).y, (hq).y, acc); \
  acc = dot2((wq).z, (hq).z, acc); acc = dot2((wq).w, (hq).w, acc);

#define REP24(X) X(0)X(1)X(2)X(3)X(4)X(5)X(6)X(7)X(8)X(9)X(10)X(11)X(12)X(13)X(14)X(15)X(16)X(17)X(18)X(19)X(20)X(21)X(22)X(23)
#define REP8(X)  X(0)X(1)X(2)X(3)X(4)X(5)X(6)X(7)

__device__ __forceinline__ void stc(float* p, float v) { *p = v; }
__device__ __forceinline__ void stc(u16* p, float v)   { *p = f2bf(v); }

// ---------------- diagnostics ----------------
__global__ void fill_sentinel_kernel(float* out, int n, float v) {
  int i = blockIdx.x * 256 + threadIdx.x;
  if (i < n) out[i] = v;
}

// ---------------- zero guards ----------------
__global__ void zero_bf_guards_kernel(u16* X0b, u16* X1b) {
  int cb = blockIdx.x, t = threadIdx.x;
  for (int c = t; c < X0S; c += 256) {
    X0b[((long)cb * PP + 0) * X0S + c] = 0;
    X0b[((long)cb * PP + PP - 1) * X0S + c] = 0;
  }
  if (t < 256) {
    X1b[((long)cb * PP + 0) * 256 + t] = 0;
    X1b[((long)cb * PP + PP - 1) * 256 + t] = 0;
  }
}
__global__ void zero_y1p_guards_kernel(u16* Y1p) {
  int b = blockIdx.x, t = threadIdx.x;
  for (int c = t; c < 512; c += 256) {
    Y1p[((long)b * NP + 0) * 512 + c] = 0;
    Y1p[((long)b * NP + NP - 1) * 512 + c] = 0;
  }
}
__global__ void zero_c3p_guards_kernel(float* C3p) {
  int b = blockIdx.x, t = threadIdx.x;
  if (t < 256) {
    C3p[((long)b * NP + 0) * 256 + t] = 0.f;
    C3p[((long)b * NP + NP - 1) * 256 + t] = 0.f;
  }
}

// ---------------- embedding (chunked, bf16 out, stride 280) ----------------
__global__ void embed_bf16_kernel(const int* __restrict__ seq, const int* __restrict__ order,
                                  const float* __restrict__ emb, const float* __restrict__ pos_emb,
                                  u16* __restrict__ X0b, int b0) {
  long i = (long)blockIdx.x * 256 + threadIdx.x;
  const long total = (long)GB * P_ * X0S;
  if (i >= total) return;
  int c = (int)(i % X0S);
  long bp = i / X0S;
  int p = (int)(bp % P_);
  int cb = (int)(bp / P_);
  int b = b0 + cb;
  float v = 0.f;
  if (c < 256)      v = emb[(long)seq[(long)b * P_ + p] * 256 + c];
  else if (c < 266) v = pos_emb[(long)order[(long)b * P_ + p] * POS_ + (c - 256)];
  X0b[((long)cb * PP + p + 1) * X0S + c] = f2bf(v);
}

// ---------------- weight repacks ----------------
__global__ void repack_conv_bt_kernel(const float* __restrict__ w, u16* __restrict__ hi,
                                      u16* __restrict__ lo, int CinReal, int strideA,
                                      int Kpad, int Cout) {
  long i = (long)blockIdx.x * 256 + threadIdx.x;
  if (i >= (long)Cout * Kpad) return;
  int co = (int)(i / Kpad), k = (int)(i - (long)co * Kpad);
  int r = k / strideA, ci = k - r * strideA;
  float v = (r < 3 && ci < CinReal) ? w[((long)co * CinReal + ci) * 3 + r] : 0.f;
  u16 h = f2bf(v);
  hi[i] = h;
  if (lo) lo[i] = f2bf(v - bf2f(h));
}
__global__ void repack_dense_bt_kernel(const float* __restrict__ w, u16* __restrict__ hi,
                                       u16* __restrict__ lo, int CinReal, int Kpad) {
  long i = (long)blockIdx.x * 256 + threadIdx.x;
  if (i >= 1024L * Kpad) return;
  int j = (int)(i / Kpad), k = (int)(i - (long)j * Kpad);
  int co = (j & 3) * 256 + (j >> 2);
  float v = (k < CinReal) ? w[(long)co * CinReal + k] : 0.f;
  u16 h = f2bf(v);
  hi[i] = h;
  lo[i] = f2bf(v - bf2f(h));
}
// Whh k<192 slice -> register-resident quads (round-8 layout)
__global__ void repack_whh_reg_kernel(const float* __restrict__ whh, uint4* __restrict__ Wv) {
  long i = (long)blockIdx.x * 256 + threadIdx.x;
  if (i >= 49152) return;
  int j = (int)(i & 511);
  int t = (int)(i >> 9);
  int kq = t % 24, rb = (t / 24) & 1, d = t / 48;
  int R = (j & 3) * 256 + (j >> 2) + rb * 128;
  const float* wr = whh + ((long)d * 1024 + R) * 256;
  uint4 o; unsigned* op = (unsigned*)&o;
#pragma unroll
  for (int q = 0; q < 4; q++) {
    int k = kq * 8 + 2 * q;
    op[q] = pack2h(wr[k], wr[k + 1]);
  }
  Wv[i] = o;
}
// Whh k in [192,256) -> LDS-resident, lane-linear (round-8 layout)
__global__ void repack_whh_lds_kernel(const float* __restrict__ whh, uint4* __restrict__ Ws) {
  long i = (long)blockIdx.x * 256 + threadIdx.x;
  if (i >= 16384) return;
  int d = (int)(i >> 13);
  int a = (int)(i & 8191);
  int rb = a >> 12;
  int rem = a & 4095;
  int i2 = rem >> 9, j = rem & 511;
  int R = (j & 3) * 256 + (j >> 2) + rb * 128;
  const float* wr = whh + ((long)d * 1024 + R) * 256;
  uint4 o; unsigned* op = (unsigned*)&o;
#pragma unroll
  for (int q = 0; q < 4; q++) {
    int k = 192 + i2 * 8 + 2 * q;
    op[q] = pack2h(wr[k], wr[k + 1]);
  }
  Ws[i] = o;
}
__global__ void bias_sum_perm_kernel(const float* __restrict__ a, const float* __restrict__ b,
                                     float* __restrict__ dst) {
  int i = blockIdx.x * 256 + threadIdx.x;
  if (i >= 2048) return;
  int d = i >> 10, j = i & 1023;
  int R = (j & 3) * 256 + (j >> 2);
  dst[i] = a[d * 1024 + R] + b[d * 1024 + R];
}
__global__ void repack_conv4_w_kernel(const float* __restrict__ w, float* __restrict__ dst) {
  int i = blockIdx.x * 256 + threadIdx.x;
  if (i < 768) { int r = i >> 8, ci = i & 255; dst[i] = w[ci * 3 + r]; }
}

// ---------------- MFMA GEMM tile, LDS-staged (round-12: padded stride, NO swizzle) ----------------
// 256 threads / 4 waves per 64x64 tile, BK=32. Stage A[64][32] + Bhi/Blo[64][32] in
// LDS with ROW STRIDE 80 B (64 data + 16 pad). Bank check: bank_start(r,s) =
// (20r+4s) mod 32 covers each bank exactly 8x over a wave's 64 b128 accesses --
// the hardware floor; true for stage-writes, A-frag reads, and all 4 B col-tile
// reads (+nt*1280 B, 320 = 0 mod 32 banks). Round-11's XOR swizzle overflowed the
// 64-B row (bit 6) -> corrupt fragments; padding is provably in-bounds.
// Global loads issued BEFORE the barrier so latency overlaps the prior MFMA phase.
// Accumulation order identical to rounds 8-10.
template <typename CT, bool SPLIT>
__device__ __forceinline__ void gemm_tile_lds(
    char* smbase, int tid, int bx, int by,
    const u16* __restrict__ A, const u16* __restrict__ Bt, const u16* __restrict__ Bt2,
    const float* __restrict__ bias, CT* __restrict__ C,
    int N, int Kpad, int Mb,
    long aBatchStride, int aRowStride,
    long cBatchStride, int cRowStride, int relu) {
  char* As = smbase;                 // 5120 B
  char* Bh = smbase + LTILE;         // 5120 B
  char* Bl = smbase + 2 * LTILE;     // 5120 B (SPLIT only)
  int wave = tid >> 6, lane = tid & 63;
  int lrow = lane & 15, lkg = lane >> 4;
  int row0 = bx * 64, col0 = by * 64;
  // staging: thread t loads 16B of row srow at k-offset skoff (halves)
  int srow = tid >> 2, skoff = (tid & 3) * 8;
  int sgrow = row0 + srow;
  int sb = sgrow / Mb, smr = sgrow - sb * Mb;
  const u16* gA  = A + (long)sb * aBatchStride + (long)smr * aRowStride + skoff;
  const u16* gBh = Bt + (long)(col0 + srow) * Kpad + skoff;
  const u16* gBl = SPLIT ? (Bt2 + (long)(col0 + srow) * Kpad + skoff) : gBh;
  int wb = srow * LROW + (tid & 3) * 16;           // in-bounds by construction
  // fragment read offsets
  int frow = wave * 16 + lrow;
  int ab  = frow * LROW + lkg * 16;
  int bb0 = lrow * LROW + lkg * 16;                // B col-tile nt adds nt*16*LROW

  f32x4 acc0 = {0.f, 0.f, 0.f, 0.f};
  f32x4 acc1 = acc0, acc2 = acc0, acc3 = acc0;
  for (int kk = 0; kk < Kpad; kk += 32) {
    s16x8 ra  = *(const s16x8*)(gA + kk);
    s16x8 rbh = *(const s16x8*)(gBh + kk);
    s16x8 rbl;
    if (SPLIT) rbl = *(const s16x8*)(gBl + kk);
    __syncthreads();                       // prior frag reads done
    *(s16x8*)(As + wb) = ra;
    *(s16x8*)(Bh + wb) = rbh;
    if (SPLIT) *(s16x8*)(Bl + wb) = rbl;
    __syncthreads();                       // writes visible
    s16x8 av = *(const s16x8*)(As + ab);
    acc0 = __builtin_amdgcn_mfma_f32_16x16x32_bf16(av, *(const s16x8*)(Bh + bb0 + 0 * (16 * LROW)), acc0, 0, 0, 0);
    acc1 = __builtin_amdgcn_mfma_f32_16x16x32_bf16(av, *(const s16x8*)(Bh + bb0 + 1 * (16 * LROW)), acc1, 0, 0, 0);
    acc2 = __builtin_amdgcn_mfma_f32_16x16x32_bf16(av, *(const s16x8*)(Bh + bb0 + 2 * (16 * LROW)), acc2, 0, 0, 0);
    acc3 = __builtin_amdgcn_mfma_f32_16x16x32_bf16(av, *(const s16x8*)(Bh + bb0 + 3 * (16 * LROW)), acc3, 0, 0, 0);
    if (SPLIT) {
      acc0 = __builtin_amdgcn_mfma_f32_16x16x32_bf16(av, *(const s16x8*)(Bl + bb0 + 0 * (16 * LROW)), acc0, 0, 0, 0);
      acc1 = __builtin_amdgcn_mfma_f32_16x16x32_bf16(av, *(const s16x8*)(Bl + bb0 + 1 * (16 * LROW)), acc1, 0, 0, 0);
      acc2 = __builtin_amdgcn_mfma_f32_16x16x32_bf16(av, *(const s16x8*)(Bl + bb0 + 2 * (16 * LROW)), acc2, 0, 0, 0);
      acc3 = __builtin_amdgcn_mfma_f32_16x16x32_bf16(av, *(const s16x8*)(Bl + bb0 + 3 * (16 * LROW)), acc3, 0, 0, 0);
    }
  }
  int erow = row0 + wave * 16 + lkg * 4;
  int b2 = erow / Mb, m2 = erow - b2 * Mb;
  CT* cbase = C + (long)b2 * cBatchStride + (long)m2 * cRowStride + col0 + lrow;
#define EPI(cc, accv) { \
    float bv = bias[col0 + (cc) * 16 + lrow]; \
    float v0 = accv[0] + bv, v1 = accv[1] + bv, v2 = accv[2] + bv, v3 = accv[3] + bv; \
    if (relu) { v0 = fmaxf(v0, 0.f); v1 = fmaxf(v1, 0.f); v2 = fmaxf(v2, 0.f); v3 = fmaxf(v3, 0.f); } \
    stc(cbase + 0L * cRowStride + (cc) * 16, v0); \
    stc(cbase + 1L * cRowStride + (cc) * 16, v1); \
    stc(cbase + 2L * cRowStride + (cc) * 16, v2); \
    stc(cbase + 3L * cRowStride + (cc) * 16, v3); }
  EPI(0, acc0) EPI(1, acc1) EPI(2, acc2) EPI(3, acc3)
#undef EPI
}

template <typename CT, bool SPLIT>
__global__ __launch_bounds__(256) void gemm_mfma_kernel(
    const u16* __restrict__ A, const u16* __restrict__ Bt, const u16* __restrict__ Bt2,
    const float* __restrict__ bias, CT* __restrict__ C,
    int N, int Kpad, int Mb,
    long aBatchStride, int aRowStride,
    long cBatchStride, int cRowStride, int relu) {
  __shared__ char smtile[GEMM_LDS];
  gemm_tile_lds<CT, SPLIT>(smtile, threadIdx.x, blockIdx.x, blockIdx.y,
                           A, Bt, Bt2, bias, C, N, Kpad, Mb,
                           aBatchStride, aRowStride, cBatchStride, cRowStride, relu);
}

// ---------------- note-segment scan: parallel runs-scan ----------------
__global__ __launch_bounds__(256) void seg_scan_kernel(const int* __restrict__ seq,
                                int* __restrict__ nstart, int* __restrict__ nlen) {
  __shared__ unsigned char v[P_];
  __shared__ int sc[2][256];
  int b = blockIdx.x, tid = threadIdx.x;
  for (int i = tid; i < P_; i += 256) {
    int s = seq[(long)b * P_ + i];
    v[i] = (s > 1 && i != P_ - 1) ? 1 : 0;   // last position never included
  }
  for (int n = tid; n < N_; n += 256) { nstart[b * N_ + n] = 0; nlen[b * N_ + n] = 0; }
  __syncthreads();
  int base = tid << 4;
  int c = 0;
#pragma unroll
  for (int i = 0; i < 16; i++) {
    int p = base + i;
    int val = v[p];
    int prev = p ? v[p - 1] : 0;
    c += val & (prev ^ 1);
  }
  sc[0][tid] = c;
  __syncthreads();
  int cur = 0;
  for (int d = 1; d < 256; d <<= 1) {
    int x = sc[cur][tid];
    if (tid >= d) x += sc[cur][tid - d];
    sc[cur ^ 1][tid] = x;
    cur ^= 1;
    __syncthreads();
  }
  int sg = tid ? sc[cur][tid - 1] : 0;
  for (int i = 0; i < 16; i++) {
    int p = base + i;
    int val = v[p];
    int prev = p ? v[p - 1] : 0;
    if (val && !prev) {
      if (sg < N_) {
        int len = 0, q = p;
        while (q < P_ && v[q]) { len++; q++; }
        nstart[b * N_ + sg] = p;
        nlen[b * N_ + sg] = len;
      }
      sg++;
    }
  }
}

// ---------------- segment mean + enc (bf16 in/out, stride 288) ----------------
__global__ __launch_bounds__(256) void agg_enc_kernel(
    const u16* __restrict__ X2b, const int* __restrict__ nstart, const int* __restrict__ nlen,
    const float* __restrict__ dur, u16* __restrict__ enc, int b0) {
  int n = blockIdx.x, gb = blockIdx.y;
  int b = b0 + gb;
  int d = threadIdx.x;
  int len = nlen[b * N_ + n], st = nstart[b * N_ + n];
  float acc = 0.f;
  for (int i = 0; i < len; i++) acc += bf2f(X2b[((long)gb * PP + st + 1 + i) * 256 + d]);
  float m = (len > 0) ? acc / (float)len : 0.f;
  long e = ((long)b * N_ + n) * ENCS;
  enc[e + d] = f2bf(m);
  if (d == 0) {
    float dd = dur[b * N_ + n];
    enc[e + 256] = f2bf(dd);
    enc[e + 257] = f2bf(1.f / (dd + 1.f));
  }
  if (d >= 2 && d < 32) enc[e + 256 + d] = 0;  // zero tail 258..287
}

// ---------------- FUSED kernel: rec (blocks 0..63) + next-chunk x-proj GEMM ----------------
// Rec body = round-8 form verbatim (best measured). Gemm blocks run the LDS-staged
// MFMA tile body on the other CUs, writing chunk rq's Z into the ping-pong buffer.
// 136KB dynamic LDS forces 1 WG/CU for rec blocks.
#define REC_LDS_BYTES (131072 + 4096 + 1024)
__global__ __attribute__((amdgpu_waves_per_eu(2, 2))) __launch_bounds__(512)
void rec_gemm_kernel(
    // rec args
    const float* __restrict__ Z,      // [2][32][TCH][1024] fp32, permuted cols
    const u32x4* __restrict__ Wv,     // [2][2][24][512] fp16 quads (k<192)
    const u32x4* __restrict__ Ws,     // [2][2][8][512] fp16 quads (k>=192)
    float* __restrict__ state,        // [64][2][256]
    u16* __restrict__ Y, int yRowsPerB, int yPad, int r,
    // gemm args (chunk rq -> Zg)
    const u16* __restrict__ Xg, const u16* __restrict__ Whg, const u16* __restrict__ Wlg,
    const float* __restrict__ bsg, float* __restrict__ Zg, int Kpg, int rq) {
  extern __shared__ char smem[];
  int tid = threadIdx.x;
  if (blockIdx.x >= 64) {
    // ---- GEMM role: two 64x64 LDS-staged tiles per 512-thread WG ----
    int half = tid >> 8, vt = tid & 255;
    int tile = (blockIdx.x - 64) * 2 + half;     // [0, 2048)
    int dir = tile >> 10;
    int t2 = tile & 1023;
    int bx = t2 & 63, by = t2 >> 6;
    int t0g = (dir == 0) ? rq * TCH : (NTCH - 1 - rq) * TCH;
    long WihD = (long)1024 * Kpg;
    long ZD = (long)B_ * TCH * 1024;
    gemm_tile_lds<float, true>(smem + half * GEMM_LDS, vt, bx, by,
        Xg + (long)t0g * Kpg, Whg + (long)dir * WihD, Wlg + (long)dir * WihD,
        bsg + dir * 1024, Zg + (long)dir * ZD,
        1024, Kpg, TCH, (long)N_ * Kpg, Kpg, (long)TCH * 1024, 1024, 0);
    return;
  }
  // ---- REC role (round-8 body) ----
  u32x4* WL = (u32x4*)smem;                              // 8192 quads
  float* zb = (float*)(smem + 131072);                   // 1024 f32
  u16*   hb = (u16*)(smem + 131072 + 4096);              // 256 fp16
  const u32x4* hb4 = (const u32x4*)hb;                   // 32 quads

  int chain = blockIdx.x;
  int d = chain >> 5, b = chain & 31;
  const float* Zb = Z + (long)(d * 32 + b) * (TCH * 1024);

  for (int iq = 0; iq < 16; ++iq) {
    int q = iq * 512 + tid;
    WL[q] = Ws[(long)d * 8192 + q];
  }
  const u32x4* WvD = Wv + (long)d * 2 * 24 * 512;
#define DECLW(i) u32x4 wA##i, wB##i;
  REP24(DECLW)
#undef DECLW
#define LOADW(i) wA##i = WvD[(i) * 512 + tid]; wB##i = WvD[(24 + (i)) * 512 + tid];
  REP24(LOADW)
#undef LOADW
#define PINW(i) asm volatile("" : "+v"(wA##i), "+v"(wB##i));
  REP24(PINW)
#undef PINW

  float h_reg = 0.f, c_reg = 0.f;
  if (tid < 256) {
    if (r > 0) {
      h_reg = state[(chain * 2 + 0) * 256 + tid];
      c_reg = state[(chain * 2 + 1) * 256 + tid];
    }
    hb[tid] = f2h_bits(h_reg);
  }
  __syncthreads();

  int t0 = (d == 0) ? r * TCH : (NTCH - 1 - r) * TCH;
  int tcf = d ? (TCH - 1) : 0;
  float preA = Zb[(long)tcf * 1024 + tid];
  float preB = Zb[(long)tcf * 1024 + 512 + tid];

  for (int tt = 0; tt < TCH; ++tt) {
    float accA = preA, accB = preB;
    if (tt + 1 < TCH) {
      int tc2 = d ? (TCH - 2 - tt) : (tt + 1);
      preA = Zb[(long)tc2 * 1024 + tid];
      preB = Zb[(long)tc2 * 1024 + 512 + tid];
    }
#define MACW(i) { u32x4 hq = hb4[i]; DOT4(accA, wA##i, hq); DOT4(accB, wB##i, hq); }
    REP24(MACW)
#undef MACW
#define MACL(i) { u32x4 hq = hb4[24 + (i)]; \
                  u32x4 qa = WL[(i) * 512 + tid]; \
                  u32x4 qb = WL[4096 + (i) * 512 + tid]; \
                  DOT4(accA, qa, hq); DOT4(accB, qb, hq); }
    REP8(MACL)
#undef MACL
    zb[tid] = accA;
    zb[tid + 512] = accB;
    __syncthreads();
    int tcur = d ? (TCH - 1 - tt) : tt;
    if (tid < 256) {
      float4 z4 = *(const float4*)&zb[tid * 4];   // (i,f,g,o) of unit tid
      float ig = sigmoidf_(z4.x), fg = sigmoidf_(z4.y);
      float gg = tanhf_(z4.z), og = sigmoidf_(z4.w);
      c_reg = fg * c_reg + ig * gg;
      float h = og * tanhf_(c_reg);
      h_reg = h;
      hb[tid] = f2h_bits(h);
      Y[((long)b * yRowsPerB + t0 + tcur + yPad) * 512 + d * 256 + tid] = f2bf(h);
    }
    __syncthreads();
  }
  if (r != NTCH - 1 && tid < 256) {
    state[(chain * 2 + 0) * 256 + tid] = h_reg;
    state[(chain * 2 + 1) * 256 + tid] = c_reg;
  }
}

// ---------------- final conv (Cout=1): wave per row ----------------
__global__ __launch_bounds__(256) void conv4_kernel(
    const float* __restrict__ C3p, const float* __restrict__ w,
    const float* __restrict__ b2, float* __restrict__ out) {
  int row = blockIdx.x * 4 + (threadIdx.x >> 6);
  int lane = threadIdx.x & 63;
  int b = row >> 10, t = row & (N_ - 1);
  const float* a = C3p + ((long)b * NP + t) * 256;
  float acc = 0.f;
  for (int k = lane; k < 768; k += 64) acc += a[k] * w[k];
  for (int off = 32; off; off >>= 1) acc += __shfl_down(acc, off, 64);
  if (lane == 0) out[row] = acc + b2[0];
}

// ---------------- host launcher ----------------
extern "C" void kernel_launch(void* const* d_in, const int* in_sizes, int n_in,
                              void* d_out, int out_size, void* d_ws, size_t ws_size,
                              hipStream_t stream) {
  const float* dur     = (const float*)d_in[0];
  const int*   seq     = (const int*)d_in[1];
  const int*   order   = (const int*)d_in[2];
  const float* emb     = (const float*)d_in[3];
  const float* pos_emb = (const float*)d_in[4];
  const float* mix_w1  = (const float*)d_in[5];
  const float* mix_b1  = (const float*)d_in[6];
  const float* mix_w2  = (const float*)d_in[7];
  const float* mix_b2  = (const float*)d_in[8];
  const float* wih0    = (const float*)d_in[9];
  const float* whh0    = (const float*)d_in[10];
  const float* bih0    = (const float*)d_in[11];
  const float* bhh0    = (const float*)d_in[12];
  const float* wih1    = (const float*)d_in[13];
  const float* whh1    = (const float*)d_in[14];
  const float* bih1    = (const float*)d_in[15];
  const float* bhh1    = (const float*)d_in[16];
  const float* cnn_w1  = (const float*)d_in[17];
  const float* cnn_b1  = (const float*)d_in[18];
  const float* cnn_w2  = (const float*)d_in[19];
  const float* cnn_b2  = (const float*)d_in[20];
  float* out = (float*)d_out;
  float* ws = (float*)d_ws;

  (void)hipFuncSetAttribute((const void*)rec_gemm_kernel,
                            hipFuncAttributeMaxDynamicSharedMemorySize, REC_LDS_BYTES);

  // ---- workspace layout (float units, 16-aligned) ----
  const long X0B_F = (long)GB * PP * X0S / 2;   // bf16 halves
  const long X1B_F = (long)GB * PP * 256 / 2;
  const long X2B_F = X1B_F;
  const long ZE2   = 2L * B_ * TCH * 1024;      // one Z ping-pong buffer (both dirs)
  const long C3P_E = (long)B_ * NP * 256;
  long region = X0B_F + X1B_F + X2B_F;
  if (2 * ZE2 > region) region = 2 * ZE2;       // two Z buffers
  if (C3P_E > region) region = C3P_E;

  long off = 0;
  auto alloc = [&](long n) { long ret = off; off += (n + 15) & ~15L; return ret; };
  long o_region = alloc(region);
  long o_enc    = alloc((long)B_ * N_ * ENCS / 2);
  long o_Y0     = alloc((long)B_ * N_ * 512 / 2);
  long o_Y1p    = alloc((long)B_ * NP * 512 / 2);
  long o_W1h    = alloc(256L * 832 / 2);
  long o_W2h    = alloc(256L * 768 / 2);
  long o_Wc1h   = alloc(256L * 1536 / 2);
  long o_Wc1l   = alloc(256L * 1536 / 2);
  long o_Wc2r   = alloc(768);
  long o_Wih0h  = alloc(2L * 1024 * ENCS / 2);
  long o_Wih0l  = alloc(2L * 1024 * ENCS / 2);
  long o_Wih1h  = alloc(2L * 1024 * 512 / 2);
  long o_Wih1l  = alloc(2L * 1024 * 512 / 2);
  long o_Wv0    = alloc(49152L * 4);
  long o_Ws0    = alloc(16384L * 4);
  long o_Wv1    = alloc(49152L * 4);
  long o_Ws1    = alloc(16384L * 4);
  long o_bs0    = alloc(2048);
  long o_bs1    = alloc(2048);
  long o_state  = alloc(64L * 2 * 256);
  long o_nst    = alloc((long)B_ * N_);
  long o_nln    = alloc((long)B_ * N_);

  if ((size_t)(off * 4) > ws_size) {
    float v = -(1000.0f + (float)(ws_size >> 20));
    fill_sentinel_kernel<<<(out_size + 255) / 256, 256, 0, stream>>>(out, out_size, v);
    return;
  }

  u16*   X0b  = (u16*)(ws + o_region);
  u16*   X1b  = (u16*)(ws + o_region + X0B_F);
  u16*   X2b  = (u16*)(ws + o_region + X0B_F + X1B_F);
  float* Zbuf[2] = { ws + o_region, ws + o_region + ZE2 };   // alias (after phase A)
  float* C3p  = ws + o_region;              // alias (after recs)
  u16*   enc  = (u16*)(ws + o_enc);
  u16*   Y0   = (u16*)(ws + o_Y0);
  u16*   Y1p  = (u16*)(ws + o_Y1p);
  u16*   W1h  = (u16*)(ws + o_W1h);
  u16*   W2h  = (u16*)(ws + o_W2h);
  u16*   Wc1h = (u16*)(ws + o_Wc1h);
  u16*   Wc1l = (u16*)(ws + o_Wc1l);
  float* Wc2r = ws + o_Wc2r;
  u16*   Wih0h = (u16*)(ws + o_Wih0h);
  u16*   Wih0l = (u16*)(ws + o_Wih0l);
  u16*   Wih1h = (u16*)(ws + o_Wih1h);
  u16*   Wih1l = (u16*)(ws + o_Wih1l);
  uint4* Wv0  = (uint4*)(ws + o_Wv0);
  uint4* Ws0  = (uint4*)(ws + o_Ws0);
  uint4* Wv1  = (uint4*)(ws + o_Wv1);
  uint4* Ws1  = (uint4*)(ws + o_Ws1);
  float* bs0  = ws + o_bs0;
  float* bs1  = ws + o_bs1;
  float* state = ws + o_state;
  int* nstart = (int*)(ws + o_nst);
  int* nlen   = (int*)(ws + o_nln);

  // ---- repacks / setup ----
  zero_bf_guards_kernel<<<GB, 256, 0, stream>>>(X0b, X1b);
  zero_y1p_guards_kernel<<<B_, 256, 0, stream>>>(Y1p);
  repack_conv_bt_kernel<<<(int)((256L * 832 + 255) / 256), 256, 0, stream>>>(
      mix_w1, W1h, nullptr, 266, X0S, 832, 256);
  repack_conv_bt_kernel<<<(int)((256L * 768 + 255) / 256), 256, 0, stream>>>(
      mix_w2, W2h, nullptr, 256, 256, 768, 256);
  repack_conv_bt_kernel<<<(int)((256L * 1536 + 255) / 256), 256, 0, stream>>>(
      cnn_w1, Wc1h, Wc1l, 512, 512, 1536, 256);
  repack_conv4_w_kernel<<<3, 256, 0, stream>>>(cnn_w2, Wc2r);
  for (int d = 0; d < 2; d++) {
    repack_dense_bt_kernel<<<(int)((1024L * ENCS + 255) / 256), 256, 0, stream>>>(
        wih0 + (long)d * 1024 * 258, Wih0h + (long)d * 1024 * ENCS,
        Wih0l + (long)d * 1024 * ENCS, 258, ENCS);
    repack_dense_bt_kernel<<<(int)((1024L * 512 + 255) / 256), 256, 0, stream>>>(
        wih1 + (long)d * 1024 * 512, Wih1h + (long)d * 1024 * 512,
        Wih1l + (long)d * 1024 * 512, 512, 512);
  }
  repack_whh_reg_kernel<<<192, 256, 0, stream>>>(whh0, Wv0);
  repack_whh_lds_kernel<<<64, 256, 0, stream>>>(whh0, Ws0);
  repack_whh_reg_kernel<<<192, 256, 0, stream>>>(whh1, Wv1);
  repack_whh_lds_kernel<<<64, 256, 0, stream>>>(whh1, Ws1);
  bias_sum_perm_kernel<<<8, 256, 0, stream>>>(bih0, bhh0, bs0);
  bias_sum_perm_kernel<<<8, 256, 0, stream>>>(bih1, bhh1, bs1);
  seg_scan_kernel<<<B_, 256, 0, stream>>>(seq, nstart, nlen);

  // ---- phase A: embed -> conv1 -> conv2 -> aggregate (8-batch chunks) ----
  for (int ch = 0; ch < NCHK; ch++) {
    int b0 = ch * GB;
    long total = (long)GB * P_ * X0S;
    embed_bf16_kernel<<<(int)((total + 255) / 256), 256, 0, stream>>>(seq, order, emb, pos_emb, X0b, b0);
    gemm_mfma_kernel<u16, false><<<dim3(GB * P_ / 64, 4), 256, 0, stream>>>(
        X0b, W1h, nullptr, mix_b1, X1b + 256,
        256, 832, P_, (long)PP * X0S, X0S, (long)PP * 256, 256, 1);
    gemm_mfma_kernel<u16, false><<<dim3(GB * P_ / 64, 4), 256, 0, stream>>>(
        X1b, W2h, nullptr, mix_b2, X2b + 256,
        256, 768, P_, (long)PP * 256, 256, (long)PP * 256, 256, 0);
    agg_enc_kernel<<<dim3(N_, GB), 256, 0, stream>>>(X2b, nstart, nlen, dur, enc, b0);
  }

  // ---- LSTM layers: prologue GEMM(chunk 0), then fused rec(r) + GEMM(r+1) ----
  const long ZD = (long)B_ * TCH * 1024;
  for (int layer = 0; layer < 2; layer++) {
    const u16*  Xl   = (layer == 0) ? enc : Y0;
    int         Kp   = (layer == 0) ? ENCS : 512;
    const u16*  Wh   = (layer == 0) ? Wih0h : Wih1h;
    const u16*  Wl   = (layer == 0) ? Wih0l : Wih1l;
    long        WihD = (long)1024 * Kp;
    const float* bsl = (layer == 0) ? bs0 : bs1;
    const u32x4* Wv  = (const u32x4*)((layer == 0) ? Wv0 : Wv1);
    const u32x4* Wsp = (const u32x4*)((layer == 0) ? Ws0 : Ws1);
    u16*        Yl   = (layer == 0) ? Y0 : Y1p;
    int         yRows = (layer == 0) ? N_ : NP;
    int         yPad  = (layer == 0) ? 0 : 1;
    // prologue: chunk 0 x-proj into Zbuf[0]
    for (int d = 0; d < 2; d++) {
      int t0 = (d == 0) ? 0 : (NTCH - 1) * TCH;
      gemm_mfma_kernel<float, true><<<dim3(B_ * TCH / 64, 16), 256, 0, stream>>>(
          Xl + (long)t0 * Kp, Wh + (long)d * WihD, Wl + (long)d * WihD,
          bsl + d * 1024, Zbuf[0] + d * ZD,
          1024, Kp, TCH, (long)N_ * Kp, Kp, (long)TCH * 1024, 1024, 0);
    }
    // fused: rec(r) on Zbuf[r&1]  ||  gemm(r+1) into Zbuf[(r+1)&1]
    for (int r = 0; r < NTCH; r++) {
      int gemmWGs = (r < NTCH - 1) ? 1024 : 0;   // 2048 tiles / 2 per WG
      rec_gemm_kernel<<<64 + gemmWGs, 512, REC_LDS_BYTES, stream>>>(
          Zbuf[r & 1], Wv, Wsp, state, Yl, yRows, yPad, r,
          Xl, Wh, Wl, bsl, Zbuf[(r + 1) & 1], Kp, r + 1);
    }
  }

  // ---- head: MFMA conv(relu) K=1536 (split weights), then 1-channel conv ----
  zero_c3p_guards_kernel<<<B_, 256, 0, stream>>>(C3p);
  gemm_mfma_kernel<float, true><<<dim3(B_ * N_ / 64, 4), 256, 0, stream>>>(
      Y1p, Wc1h, Wc1l, cnn_b1, C3p + 256,
      256, 1536, N_, (long)NP * 512, 512, (long)NP * 256, 256, 1);
  conv4_kernel<<<B_ * N_ / 4, 256, 0, stream>>>(C3p, Wc2r, cnn_b2, out);
}